// Round 1
// 1073.918 us; speedup vs baseline: 1.1744x; 1.1744x over previous
//
#include <hip/hip_runtime.h>
#include <hip/hip_bf16.h>
#include <stdint.h>

// Problem constants
//  L=4, MM=2, C=128, H=64, OUTC=128, EDGE_CH=128, X_EDGE=384, C3=384
//  NRED=19, NFULL=25, E=10000
//  Effective w_m0 rows 512..1087 (576 outs, padded to 640)

__constant__ int c_MASKP[19] = {0,2,6,12,20, 3,7,13,21, 1,5,11,19, 8,14,22, 4,10,18};
__constant__ int c_GATEP[19] = {-1,0,1,2,3, 0,1,2,3, 0,1,2,3, 1,2,3, 1,2,3};
__constant__ int c_LFULL[25] = {0,1,1,1,2,2,2,2,2,3,3,3,3,3,3,3,4,4,4,4,4,4,4,4,4};

__device__ __forceinline__ float sigm_(float x) { return 1.f / (1.f + __expf(-x)); }

typedef __attribute__((ext_vector_type(8))) __bf16 bf16x8;
typedef __attribute__((ext_vector_type(4))) float floatx4;

__device__ __forceinline__ void async16(const void* g, void* l) {
    __builtin_amdgcn_global_load_lds(
        (__attribute__((address_space(1))) void*)(g),
        (__attribute__((address_space(3))) void*)(l), 16, 0, 0);
}

// ---------------------------------------------------------------------------
// K0': split proj_w (5,128,64) fp32 -> pwb (5,128,192) bf16 as [hi | lo | hi]
// (pairs with A rows stored [hi | hi | lo] so that A.B = ah*bh + ah*bl + al*bh
//  ~ full fp32 product; dropped al*bl term is O(2^-18) relative)
__global__ void k_split_pw(const float* __restrict__ pw, __hip_bfloat16* __restrict__ pwb) {
    int d = blockIdx.x * 256 + threadIdx.x;
    if (d >= 40960) return;                 // 5*128*64
    int ll = d >> 13, rem = d & 8191;
    int o = rem >> 6, i = rem & 63;
    float v = pw[d];
    __hip_bfloat16 hi = __float2bfloat16(v);
    __hip_bfloat16 lo = __float2bfloat16(v - __bfloat162float(hi));
    long ob = (long)(ll * 128 + o) * 192;
    pwb[ob + i]       = hi;
    pwb[ob + 64 + i]  = lo;
    pwb[ob + 128 + i] = hi;
}

// ---------------------------------------------------------------------------
// Kc: fp32 weight [rows][K] -> bf16 [rowsPad][K], pad rows zero
__global__ void k_cvt_w(const float* __restrict__ W, __hip_bfloat16* __restrict__ out,
                        int rows, int rowsPad, int K) {
    long i = (long)blockIdx.x * 256 + threadIdx.x;
    if (i >= (long)rowsPad * K) return;
    int r = (int)(i / K);
    out[i] = __float2bfloat16(r < rows ? W[i] : 0.f);
}

// ---------------------------------------------------------------------------
// K1: radial MLP front: x_edge -> silu(LN(.@w1^T)) -> silu(LN(.@w2^T)) -> bf16
__global__ __launch_bounds__(256) void k_radial_front(
    const float* __restrict__ ed, const float* __restrict__ se, const float* __restrict__ te,
    const float* __restrict__ w1, const float* __restrict__ b1,
    const float* __restrict__ g1, const float* __restrict__ bb1,
    const float* __restrict__ w2, const float* __restrict__ b2,
    const float* __restrict__ g2, const float* __restrict__ bb2,
    const int* __restrict__ an, const int* __restrict__ eidx,
    __hip_bfloat16* __restrict__ h2out, int e0, int ec, int E)
{
    __shared__ float xe[8 * 384];
    __shared__ float hb[8 * 128];
    __shared__ float hb2[8 * 128];
    __shared__ float stats[8][2];
    int tid = threadIdx.x;
    int ebase = e0 + blockIdx.x * 8;
    int elim = e0 + ec;

    for (int idx = tid; idx < 8 * 384; idx += 256) {
        int es = idx / 384, c = idx - es * 384;
        int e = ebase + es;
        float v = 0.f;
        if (e < elim) {
            if (c < 128)       v = ed[(long)e * 128 + c];
            else if (c < 256)  { int s = eidx[e];     v = se[an[s] * 128 + (c - 128)]; }
            else               { int t = eidx[E + e]; v = te[an[t] * 128 + (c - 256)]; }
        }
        xe[idx] = v;
    }
    __syncthreads();

    int o = tid & 127;
    int half = tid >> 7;
    for (int pass = 0; pass < 4; ++pass) {
        int es = pass * 2 + half;
        float acc = b1[o];
        const float4* wr = (const float4*)(w1 + (long)o * 384);
        const float4* xr = (const float4*)(xe + es * 384);
        #pragma unroll 8
        for (int k = 0; k < 96; ++k) {
            float4 w = wr[k], xv = xr[k];
            acc += w.x * xv.x + w.y * xv.y + w.z * xv.z + w.w * xv.w;
        }
        hb[es * 128 + o] = acc;
    }
    __syncthreads();
    if (tid < 8) {
        float s = 0.f, s2 = 0.f;
        for (int k = 0; k < 128; ++k) { float v = hb[tid * 128 + k]; s += v; s2 += v * v; }
        float mu = s * (1.f / 128.f);
        float var = s2 * (1.f / 128.f) - mu * mu;
        stats[tid][0] = mu;
        stats[tid][1] = rsqrtf(var + 1e-5f);
    }
    __syncthreads();
    for (int idx = tid; idx < 1024; idx += 256) {
        int es = idx >> 7, c = idx & 127;
        float v = (hb[idx] - stats[es][0]) * stats[es][1] * g1[c] + bb1[c];
        hb[idx] = v * sigm_(v);
    }
    __syncthreads();
    for (int pass = 0; pass < 4; ++pass) {
        int es = pass * 2 + half;
        float acc = b2[o];
        const float4* wr = (const float4*)(w2 + (long)o * 128);
        const float4* xr = (const float4*)(hb + es * 128);
        #pragma unroll 8
        for (int k = 0; k < 32; ++k) {
            float4 w = wr[k], xv = xr[k];
            acc += w.x * xv.x + w.y * xv.y + w.z * xv.z + w.w * xv.w;
        }
        hb2[es * 128 + o] = acc;
    }
    __syncthreads();
    if (tid < 8) {
        float s = 0.f, s2 = 0.f;
        for (int k = 0; k < 128; ++k) { float v = hb2[tid * 128 + k]; s += v; s2 += v * v; }
        float mu = s * (1.f / 128.f);
        float var = s2 * (1.f / 128.f) - mu * mu;
        stats[tid][0] = mu;
        stats[tid][1] = rsqrtf(var + 1e-5f);
    }
    __syncthreads();
    for (int idx = tid; idx < 1024; idx += 256) {
        int es = idx >> 7, c = idx & 127;
        int e = ebase + es;
        if (e < elim) {
            float v = (hb2[idx] - stats[es][0]) * stats[es][1] * g2[c] + bb2[c];
            v = v * sigm_(v);
            h2out[(long)(e - e0) * 128 + c] = __float2bfloat16(v);
        }
    }
}

// ---------------------------------------------------------------------------
// MFMA GEMM (m97 structure): Out[r][o] = sum_k A[r][k]*B[o][k] (+bias[o])
// A: bf16 [Mpad][K], B: bf16 [Npad][K]; grid (Mpad/128, Npad/128); 256 thr.
__global__ __launch_bounds__(256) void k_mfma_gemm(
    const __hip_bfloat16* __restrict__ A,
    const __hip_bfloat16* __restrict__ B,
    const float* __restrict__ bias,
    float* __restrict__ Out, int ldo,
    int realM, int realN, int K)
{
    __shared__ __align__(16) __hip_bfloat16 As[128 * 32];
    __shared__ __align__(16) __hip_bfloat16 Bs[128 * 32];
    int tid = threadIdx.x;
    int l = tid & 63, w = tid >> 6;
    int r0 = blockIdx.x * 128, n0 = blockIdx.y * 128;
    int wm = w & 1, wn = w >> 1;

    floatx4 acc[4][4] = {};

    int srow = w * 16 + (l >> 2);
    int scol = (l & 3) * 8;
    const __hip_bfloat16* Ag = A + (long)(r0 + srow) * K + scol;
    const __hip_bfloat16* Bg = B + (long)(n0 + srow) * K + scol;
    __hip_bfloat16* AsW = As + (w * 16) * 32;
    __hip_bfloat16* BsW = Bs + (w * 16) * 32;

    int lrow = l & 15, lk = (l >> 4) * 8;

    for (int kk = 0; kk < K; kk += 32) {
        async16(Ag + kk, AsW);
        async16(Ag + (long)64 * K + kk, AsW + 64 * 32);
        async16(Bg + kk, BsW);
        async16(Bg + (long)64 * K + kk, BsW + 64 * 32);
        __syncthreads();
        bf16x8 af[4], bf[4];
        #pragma unroll
        for (int mi = 0; mi < 4; ++mi)
            af[mi] = *(const bf16x8*)&As[(wm * 64 + mi * 16 + lrow) * 32 + lk];
        #pragma unroll
        for (int ni = 0; ni < 4; ++ni)
            bf[ni] = *(const bf16x8*)&Bs[(wn * 64 + ni * 16 + lrow) * 32 + lk];
        #pragma unroll
        for (int mi = 0; mi < 4; ++mi)
            #pragma unroll
            for (int ni = 0; ni < 4; ++ni)
                acc[mi][ni] = __builtin_amdgcn_mfma_f32_16x16x32_bf16(
                    af[mi], bf[ni], acc[mi][ni], 0, 0, 0);
        __syncthreads();
    }

    int lq = l >> 4;
    #pragma unroll
    for (int ni = 0; ni < 4; ++ni) {
        int col = n0 + wn * 64 + ni * 16 + lrow;
        if (col >= realN) continue;
        float bv = bias ? bias[col] : 0.f;
        #pragma unroll
        for (int mi = 0; mi < 4; ++mi) {
            int rbase = r0 + wm * 64 + mi * 16 + lq * 4;
            floatx4 v = acc[mi][ni];
            #pragma unroll
            for (int r = 0; r < 4; ++r) {
                int row = rbase + r;
                if (row < realM) Out[(long)row * ldo + col] = v[r] + bv;
            }
        }
    }
}

// ---------------------------------------------------------------------------
// K3 (register version): per edge, thread c streams n=0..24:
//   one coalesced global load, scale by reg-held rad[l], accumulate 19
//   register accs with broadcast LDS reads of pre-permuted Wigner rows.
__global__ __launch_bounds__(384) void k_build_mp(
    const float* __restrict__ x, const float* __restrict__ ef, const float* __restrict__ wgn,
    const float* __restrict__ wrad, const int* __restrict__ eidx,
    __hip_bfloat16* __restrict__ A0, __hip_bfloat16* __restrict__ A1,
    __hip_bfloat16* __restrict__ A2, int e0, int E)
{
    __shared__ float swig[475];   // 19 permuted rows x 25
    int tid = threadIdx.x;
    int le = blockIdx.x;
    long e = e0 + le;
    int src = eidx[e], tgt = eidx[E + e];

    for (int i = tid; i < 475; i += 384) {
        int j = i / 25, n = i - j * 25;
        swig[i] = wgn[e * 625 + c_MASKP[j] * 25 + n];
    }

    int c = tid;  // 0..383 (wave-uniform branch: waves 0-1 src, 2-3 tgt, 4-5 ef)
    float rad[5];
    #pragma unroll
    for (int l = 0; l < 5; ++l) rad[l] = wrad[(long)le * 1920 + l * 384 + c];

    const float* base;
    if (c < 128)      base = x  + (long)src * 3200 + c;
    else if (c < 256) base = x  + (long)tgt * 3200 + (c - 128);
    else              base = ef + e * 3200 + (c - 256);

    __syncthreads();

    float acc[19] = {};
    #pragma unroll
    for (int n = 0; n < 25; ++n) {
        float v = base[n * 128] * rad[c_LFULL[n]];
        #pragma unroll
        for (int j = 0; j < 19; ++j)
            acc[j] += swig[j * 25 + n] * v;
    }

    #pragma unroll
    for (int j = 0; j < 19; ++j) {
        __hip_bfloat16 hv = __float2bfloat16(acc[j]);
        if (j < 5)       A0[(long)le * 1920 + j * 384 + c] = hv;
        else if (j < 9)  A1[(long)(2 * le)     * 1536 + (j - 5)  * 384 + c] = hv;
        else if (j < 13) A1[(long)(2 * le + 1) * 1536 + (j - 9)  * 384 + c] = hv;
        else if (j < 16) A2[(long)(2 * le)     * 1152 + (j - 13) * 384 + c] = hv;
        else             A2[(long)(2 * le + 1) * 1152 + (j - 16) * 384 + c] = hv;
    }
}

// ---------------------------------------------------------------------------
// K5a: recombine + gate + transposed Wigner -> sful as split-bf16 rows.
// Row (e, l, ni) stored at sfl[(CE*l^2 + le*(2l+1) + ni)*192] as [hi|hi|lo].
__global__ __launch_bounds__(256) void k_combine_a(
    const float* __restrict__ wgn, const float* __restrict__ ym0,
    const float* __restrict__ ym1, const float* __restrict__ ym2,
    __hip_bfloat16* __restrict__ sfl, int e0, int CE)
{
    __shared__ float swig[475];   // 19 permuted rows x 25
    __shared__ float shl[1216];   // 19 x 64
    int tid = threadIdx.x;
    int le = blockIdx.x;
    long e = e0 + le;

    for (int i = tid; i < 475; i += 256) {
        int j = i / 25, n = i - j * 25;
        swig[i] = wgn[e * 625 + c_MASKP[j] * 25 + n];
    }

    const float* y0  = ym0 + (long)le * 576;
    const float* y1a = ym1 + (long)(2 * le) * 512;
    const float* y1b = ym1 + (long)(2 * le + 1) * 512;
    const float* y2a = ym2 + (long)(2 * le) * 384;
    const float* y2b = ym2 + (long)(2 * le + 1) * 384;

    for (int i = tid; i < 1216; i += 256) {
        int j = i >> 6, c = i & 63;
        float raw;
        if (j < 5)        raw = y0[256 + j * 64 + c];
        else if (j < 9)   { int k = (j - 5) * 64 + c;  raw = y1a[k] - y1b[256 + k]; }
        else if (j < 13)  { int k = (j - 9) * 64 + c;  raw = y1b[k] + y1a[256 + k]; }
        else if (j < 16)  { int k = (j - 13) * 64 + c; raw = y2a[k] - y2b[192 + k]; }
        else              { int k = (j - 16) * 64 + c; raw = y2b[k] + y2a[192 + k]; }
        float v;
        if (j == 0) v = raw * sigm_(raw);
        else        v = raw * sigm_(y0[c_GATEP[j] * 64 + c]);
        shl[i] = v;
    }
    __syncthreads();

    for (int i = tid; i < 1600; i += 256) {
        int n = i >> 6, c = i & 63;          // n uniform per wave -> swig broadcast
        float acc = 0.f;
        #pragma unroll
        for (int j = 0; j < 19; ++j) acc += swig[j * 25 + n] * shl[j * 64 + c];
        __hip_bfloat16 hi = __float2bfloat16(acc);
        __hip_bfloat16 lo = __float2bfloat16(acc - __bfloat162float(hi));
        int l = c_LFULL[n];
        int nb = l * l, cnt = 2 * l + 1, ni = n - nb;
        long row = (long)CE * nb + (long)le * cnt + ni;
        sfl[row * 192 + c]       = hi;
        sfl[row * 192 + 64 + c]  = hi;
        sfl[row * 192 + 128 + c] = lo;
    }
}

// ---------------------------------------------------------------------------
// K5b: merged projection GEMM over all 5 l-segments.
//   out[e,nb+ni,o] = sum_i sful[e,nb+ni,i] * pw[l][o,i]  (+pb[o] for l=0)
// A = sfl split rows (K=192), B = pwb (K=192). One tile row per block.
__global__ __launch_bounds__(256) void k_proj_gemm(
    const __hip_bfloat16* __restrict__ sfl,
    const __hip_bfloat16* __restrict__ pwb,
    const float* __restrict__ pb,
    float* __restrict__ out, int ec, int CE)
{
    __shared__ __align__(16) __hip_bfloat16 As[128 * 32];
    __shared__ __align__(16) __hip_bfloat16 Bs[128 * 32];
    int tid = threadIdx.x;
    int ln = tid & 63, w = tid >> 6;
    int wm = w & 1, wn = w >> 1;

    // locate l-segment (monotone scan, no break)
    int bid = blockIdx.x;
    int l = 0, base = 0;
    #pragma unroll
    for (int ll = 0; ll < 5; ++ll) {
        int tiles = (ec * (2 * ll + 1) + 127) >> 7;
        if (bid >= base + tiles) { base += tiles; l = ll + 1; }
    }
    if (l > 4) return;
    int cnt = 2 * l + 1, nb = l * l;
    int realM = ec * cnt;
    int r0 = (bid - base) * 128;

    const __hip_bfloat16* A = sfl + (long)CE * nb * 192;
    const __hip_bfloat16* B = pwb + l * 128 * 192;

    floatx4 acc[4][4] = {};

    int srow = w * 16 + (ln >> 2);
    int scol = (ln & 3) * 8;
    const __hip_bfloat16* Ag = A + (long)(r0 + srow) * 192 + scol;
    const __hip_bfloat16* Bg = B + (long)srow * 192 + scol;
    __hip_bfloat16* AsW = As + (w * 16) * 32;
    __hip_bfloat16* BsW = Bs + (w * 16) * 32;

    int lrow = ln & 15, lk = (ln >> 4) * 8;

    for (int kk = 0; kk < 192; kk += 32) {
        async16(Ag + kk, AsW);
        async16(Ag + (long)64 * 192 + kk, AsW + 64 * 32);
        async16(Bg + kk, BsW);
        async16(Bg + (long)64 * 192 + kk, BsW + 64 * 32);
        __syncthreads();
        bf16x8 af[4], bf[4];
        #pragma unroll
        for (int mi = 0; mi < 4; ++mi)
            af[mi] = *(const bf16x8*)&As[(wm * 64 + mi * 16 + lrow) * 32 + lk];
        #pragma unroll
        for (int ni = 0; ni < 4; ++ni)
            bf[ni] = *(const bf16x8*)&Bs[(wn * 64 + ni * 16 + lrow) * 32 + lk];
        #pragma unroll
        for (int mi = 0; mi < 4; ++mi)
            #pragma unroll
            for (int ni = 0; ni < 4; ++ni)
                acc[mi][ni] = __builtin_amdgcn_mfma_f32_16x16x32_bf16(
                    af[mi], bf[ni], acc[mi][ni], 0, 0, 0);
        __syncthreads();
    }

    int lq = ln >> 4;
    #pragma unroll
    for (int mi = 0; mi < 4; ++mi) {
        #pragma unroll
        for (int r = 0; r < 4; ++r) {
            int row = r0 + wm * 64 + mi * 16 + lq * 4 + r;
            if (row >= realM) continue;
            int e = row / cnt;
            int nn = nb + (row - e * cnt);
            float* op = out + (long)e * 3200 + (long)nn * 128;
            #pragma unroll
            for (int nib = 0; nib < 4; ++nib) {
                int col = wn * 64 + nib * 16 + lrow;
                float bv = (l == 0) ? pb[col] : 0.f;
                op[col] = acc[mi][nib][r] + bv;
            }
        }
    }
}

// ---------------------------------------------------------------------------
extern "C" void kernel_launch(void* const* d_in, const int* in_sizes, int n_in,
                              void* d_out, int out_size, void* d_ws, size_t ws_size,
                              hipStream_t stream)
{
    const float* x    = (const float*)d_in[0];
    const float* ef   = (const float*)d_in[1];
    const float* ed   = (const float*)d_in[2];
    const float* wgn  = (const float*)d_in[3];
    const float* se   = (const float*)d_in[4];
    const float* te   = (const float*)d_in[5];
    const float* w1   = (const float*)d_in[6];
    const float* b1   = (const float*)d_in[7];
    const float* g1   = (const float*)d_in[8];
    const float* bb1  = (const float*)d_in[9];
    const float* w2   = (const float*)d_in[10];
    const float* b2   = (const float*)d_in[11];
    const float* g2   = (const float*)d_in[12];
    const float* bb2  = (const float*)d_in[13];
    const float* w3   = (const float*)d_in[14];
    const float* b3   = (const float*)d_in[15];
    const float* wm0  = (const float*)d_in[16];
    const float* bm0  = (const float*)d_in[17];
    const float* wm1  = (const float*)d_in[18];
    const float* wm2  = (const float*)d_in[19];
    const float* pw   = (const float*)d_in[20];
    const float* pb   = (const float*)d_in[21];
    const int*   an   = (const int*)d_in[22];
    const int*   eidx = (const int*)d_in[23];
    float* out = (float*)d_out;
    char*  ws  = (char*)d_ws;

    const int E = in_sizes[23] / 2;           // 10000

    size_t off = 0;
    __hip_bfloat16* pwb = (__hip_bfloat16*)(ws + off); off += 5L * 128 * 192 * 2;
    __hip_bfloat16* Wb0 = (__hip_bfloat16*)(ws + off); off += 640L  * 1920 * 2;
    __hip_bfloat16* Wb1 = (__hip_bfloat16*)(ws + off); off += 512L  * 1536 * 2;
    __hip_bfloat16* Wb2 = (__hip_bfloat16*)(ws + off); off += 384L  * 1152 * 2;
    __hip_bfloat16* Wb3 = (__hip_bfloat16*)(ws + off); off += 1920L * 128  * 2;
    size_t fixedBytes = off;

    // per-edge chunk bytes: 32000 (old) + 9600 (sfl split rows) = 41600
    long usable = (long)ws_size - (long)fixedBytes;
    long ceRaw = usable / 41600;
    long Epad = ((long)E + 127) & ~127L;
    long CE = ceRaw & ~127L;
    if (CE > Epad) CE = Epad;
    if (CE < 128) CE = 128;

    __hip_bfloat16* h2b = (__hip_bfloat16*)(ws + off); off += CE * 128 * 2;
    float* wrad = (float*)(ws + off);                  off += CE * 1920 * 4;
    __hip_bfloat16* A0 = (__hip_bfloat16*)(ws + off);  off += CE * 1920 * 2;
    __hip_bfloat16* A1 = (__hip_bfloat16*)(ws + off);  off += 2 * CE * 1536 * 2;
    __hip_bfloat16* A2 = (__hip_bfloat16*)(ws + off);  off += 2 * CE * 1152 * 2;
    float* y0 = (float*)(ws + off);                    off += CE * 576 * 4;
    float* y1 = (float*)(ws + off);                    off += 2 * CE * 512 * 4;
    float* y2 = (float*)(ws + off);                    off += 2 * CE * 384 * 4;
    __hip_bfloat16* sfl = (__hip_bfloat16*)(ws + off); off += CE * 25 * 192 * 2;

    k_split_pw<<<160, 256, 0, stream>>>(pw, pwb);
    k_cvt_w<<<(640 * 1920 + 255) / 256, 256, 0, stream>>>(wm0 + 512L * 1920, Wb0, 576, 640, 1920);
    k_cvt_w<<<(512 * 1536 + 255) / 256, 256, 0, stream>>>(wm1, Wb1, 512, 512, 1536);
    k_cvt_w<<<(384 * 1152 + 255) / 256, 256, 0, stream>>>(wm2, Wb2, 384, 384, 1152);
    k_cvt_w<<<(1920 * 128 + 255) / 256, 256, 0, stream>>>(w3, Wb3, 1920, 1920, 128);

    for (int e0 = 0; e0 < E; e0 += (int)CE) {
        int ec = (E - e0 < (int)CE) ? (E - e0) : (int)CE;
        int Mp  = (ec + 127) & ~127;
        int Mp2 = (2 * ec + 127) & ~127;

        k_radial_front<<<dim3((ec + 7) / 8), 256, 0, stream>>>(
            ed, se, te, w1, b1, g1, bb1, w2, b2, g2, bb2, an, eidx, h2b, e0, ec, E);

        k_mfma_gemm<<<dim3(Mp / 128, 1920 / 128), 256, 0, stream>>>(
            h2b, Wb3, b3, wrad, 1920, ec, 1920, 128);

        k_build_mp<<<dim3(ec), 384, 0, stream>>>(x, ef, wgn, wrad, eidx, A0, A1, A2, e0, E);

        k_mfma_gemm<<<dim3(Mp / 128, 640 / 128), 256, 0, stream>>>(
            A0, Wb0, bm0 + 512, y0, 576, ec, 576, 1920);
        k_mfma_gemm<<<dim3(Mp2 / 128, 512 / 128), 256, 0, stream>>>(
            A1, Wb1, (const float*)nullptr, y1, 512, 2 * ec, 512, 1536);
        k_mfma_gemm<<<dim3(Mp2 / 128, 384 / 128), 256, 0, stream>>>(
            A2, Wb2, (const float*)nullptr, y2, 384, 2 * ec, 384, 1152);

        k_combine_a<<<dim3(ec), 256, 0, stream>>>(wgn, y0, y1, y2, sfl, e0, (int)CE);

        int tilesTot = 0;
        for (int l = 0; l < 5; ++l) tilesTot += (ec * (2 * l + 1) + 127) >> 7;
        k_proj_gemm<<<dim3(tilesTot), 256, 0, stream>>>(
            sfl, pwb, pb, out + (long)e0 * 3200, ec, (int)CE);
    }
}

// Round 2
// 864.944 us; speedup vs baseline: 1.4581x; 1.2416x over previous
//
#include <hip/hip_runtime.h>
#include <hip/hip_bf16.h>
#include <stdint.h>

// Problem constants
//  L=4, MM=2, C=128, H=64, OUTC=128, EDGE_CH=128, X_EDGE=384, C3=384
//  NRED=19, NFULL=25, E=10000
//  Effective w_m0 rows 512..1087 (576 outs, padded to 640)

__constant__ int c_MASKP[19] = {0,2,6,12,20, 3,7,13,21, 1,5,11,19, 8,14,22, 4,10,18};
__constant__ int c_GATEP[19] = {-1,0,1,2,3, 0,1,2,3, 0,1,2,3, 1,2,3, 1,2,3};
__constant__ int c_LFULL[25] = {0,1,1,1,2,2,2,2,2,3,3,3,3,3,3,3,4,4,4,4,4,4,4,4,4};

__device__ __forceinline__ float sigm_(float x) { return 1.f / (1.f + __expf(-x)); }

typedef __attribute__((ext_vector_type(8))) __bf16 bf16x8;
typedef __attribute__((ext_vector_type(4))) float floatx4;

__device__ __forceinline__ void async16(const void* g, void* l) {
    __builtin_amdgcn_global_load_lds(
        (__attribute__((address_space(1))) void*)(g),
        (__attribute__((address_space(3))) void*)(l), 16, 0, 0);
}

// ---------------------------------------------------------------------------
// K0': split proj_w (5,128,64) fp32 -> pwb (5,128,192) bf16 as [hi | lo | hi]
// (pairs with A rows stored [hi | hi | lo] so that A.B = ah*bh + ah*bl + al*bh
//  ~ full fp32 product; dropped al*bl term is O(2^-18) relative)
__global__ void k_split_pw(const float* __restrict__ pw, __hip_bfloat16* __restrict__ pwb) {
    int d = blockIdx.x * 256 + threadIdx.x;
    if (d >= 40960) return;                 // 5*128*64
    int ll = d >> 13, rem = d & 8191;
    int o = rem >> 6, i = rem & 63;
    float v = pw[d];
    __hip_bfloat16 hi = __float2bfloat16(v);
    __hip_bfloat16 lo = __float2bfloat16(v - __bfloat162float(hi));
    long ob = (long)(ll * 128 + o) * 192;
    pwb[ob + i]       = hi;
    pwb[ob + 64 + i]  = lo;
    pwb[ob + 128 + i] = hi;
}

// ---------------------------------------------------------------------------
// Kc: fp32 weight [rows][K] -> bf16 [rowsPad][K], pad rows zero
__global__ void k_cvt_w(const float* __restrict__ W, __hip_bfloat16* __restrict__ out,
                        int rows, int rowsPad, int K) {
    long i = (long)blockIdx.x * 256 + threadIdx.x;
    if (i >= (long)rowsPad * K) return;
    int r = (int)(i / K);
    out[i] = __float2bfloat16(r < rows ? W[i] : 0.f);
}

// ---------------------------------------------------------------------------
// Kc': fp32 weight [rows][K] -> split bf16 [rows][3K] = [hi | lo | hi]
__global__ void k_cvt_w_split(const float* __restrict__ W, __hip_bfloat16* __restrict__ out,
                              int rows, int K) {
    long i = (long)blockIdx.x * 256 + threadIdx.x;
    if (i >= (long)rows * K) return;
    int r = (int)(i / K), k = (int)(i - (long)r * K);
    float v = W[i];
    __hip_bfloat16 hi = __float2bfloat16(v);
    __hip_bfloat16 lo = __float2bfloat16(v - __bfloat162float(hi));
    long ob = (long)r * 3 * K;
    out[ob + k]         = hi;
    out[ob + K + k]     = lo;
    out[ob + 2 * K + k] = hi;
}

// ---------------------------------------------------------------------------
// K1a: gather x_edge = [ed | se[an[src]] | te[an[tgt]]] -> split bf16 [CE][1152]
// rows stored [hi(384) | hi(384) | lo(384)]
__global__ __launch_bounds__(256) void k_build_xedge(
    const float* __restrict__ ed, const float* __restrict__ se, const float* __restrict__ te,
    const int* __restrict__ an, const int* __restrict__ eidx,
    __hip_bfloat16* __restrict__ xeb, int e0, int ec, int E)
{
    long i = (long)blockIdx.x * 256 + threadIdx.x;
    if (i >= (long)ec * 384) return;
    int le = (int)(i / 384), c = (int)(i - (long)le * 384);
    int e = e0 + le;
    float v;
    if (c < 128)       v = ed[(long)e * 128 + c];
    else if (c < 256)  { int s = eidx[e];     v = se[an[s] * 128 + (c - 128)]; }
    else               { int t = eidx[E + e]; v = te[an[t] * 128 + (c - 256)]; }
    __hip_bfloat16 hi = __float2bfloat16(v);
    __hip_bfloat16 lo = __float2bfloat16(v - __bfloat162float(hi));
    long ob = (long)le * 1152;
    xeb[ob + c]       = hi;
    xeb[ob + 384 + c] = hi;
    xeb[ob + 768 + c] = lo;
}

// ---------------------------------------------------------------------------
// K1b: per-row LayerNorm + SiLU on fp32 [ec][128].
// split==1: write split-bf16 rows [hi(128)|hi(128)|lo(128)] (ld 384)
// split==0: write plain bf16 rows (ld 128)
__global__ __launch_bounds__(256) void k_ln_silu(
    const float* __restrict__ H, const float* __restrict__ g, const float* __restrict__ bb,
    __hip_bfloat16* __restrict__ out, int ec, int split)
{
    int row = blockIdx.x * 4 + (threadIdx.x >> 6);
    if (row >= ec) return;
    int lane = threadIdx.x & 63;
    const float* hr = H + (long)row * 128;
    float v0 = hr[lane], v1 = hr[lane + 64];
    float s = v0 + v1, s2 = v0 * v0 + v1 * v1;
    #pragma unroll
    for (int o = 32; o >= 1; o >>= 1) {
        s  += __shfl_xor(s, o, 64);
        s2 += __shfl_xor(s2, o, 64);
    }
    float mu = s * (1.f / 128.f);
    float rs = rsqrtf(s2 * (1.f / 128.f) - mu * mu + 1e-5f);
    float a0 = (v0 - mu) * rs * g[lane]      + bb[lane];
    float a1 = (v1 - mu) * rs * g[lane + 64] + bb[lane + 64];
    a0 = a0 * sigm_(a0);
    a1 = a1 * sigm_(a1);
    if (split) {
        long ob = (long)row * 384;
        __hip_bfloat16 h0 = __float2bfloat16(a0);
        __hip_bfloat16 l0 = __float2bfloat16(a0 - __bfloat162float(h0));
        __hip_bfloat16 h1 = __float2bfloat16(a1);
        __hip_bfloat16 l1 = __float2bfloat16(a1 - __bfloat162float(h1));
        out[ob + lane]            = h0;
        out[ob + 128 + lane]      = h0;
        out[ob + 256 + lane]      = l0;
        out[ob + lane + 64]       = h1;
        out[ob + 128 + lane + 64] = h1;
        out[ob + 256 + lane + 64] = l1;
    } else {
        long ob = (long)row * 128;
        out[ob + lane]      = __float2bfloat16(a0);
        out[ob + lane + 64] = __float2bfloat16(a1);
    }
}

// ---------------------------------------------------------------------------
// MFMA GEMM (m97 structure): Out[r][o] = sum_k A[r][k]*B[o][k] (+bias[o])
// A: bf16 [Mpad][K], B: bf16 [Npad][K]; grid (Mpad/128, Npad/128); 256 thr.
__global__ __launch_bounds__(256) void k_mfma_gemm(
    const __hip_bfloat16* __restrict__ A,
    const __hip_bfloat16* __restrict__ B,
    const float* __restrict__ bias,
    float* __restrict__ Out, int ldo,
    int realM, int realN, int K)
{
    __shared__ __align__(16) __hip_bfloat16 As[128 * 32];
    __shared__ __align__(16) __hip_bfloat16 Bs[128 * 32];
    int tid = threadIdx.x;
    int l = tid & 63, w = tid >> 6;
    int r0 = blockIdx.x * 128, n0 = blockIdx.y * 128;
    int wm = w & 1, wn = w >> 1;

    floatx4 acc[4][4] = {};

    int srow = w * 16 + (l >> 2);
    int scol = (l & 3) * 8;
    const __hip_bfloat16* Ag = A + (long)(r0 + srow) * K + scol;
    const __hip_bfloat16* Bg = B + (long)(n0 + srow) * K + scol;
    __hip_bfloat16* AsW = As + (w * 16) * 32;
    __hip_bfloat16* BsW = Bs + (w * 16) * 32;

    int lrow = l & 15, lk = (l >> 4) * 8;

    for (int kk = 0; kk < K; kk += 32) {
        async16(Ag + kk, AsW);
        async16(Ag + (long)64 * K + kk, AsW + 64 * 32);
        async16(Bg + kk, BsW);
        async16(Bg + (long)64 * K + kk, BsW + 64 * 32);
        __syncthreads();
        bf16x8 af[4], bf[4];
        #pragma unroll
        for (int mi = 0; mi < 4; ++mi)
            af[mi] = *(const bf16x8*)&As[(wm * 64 + mi * 16 + lrow) * 32 + lk];
        #pragma unroll
        for (int ni = 0; ni < 4; ++ni)
            bf[ni] = *(const bf16x8*)&Bs[(wn * 64 + ni * 16 + lrow) * 32 + lk];
        #pragma unroll
        for (int mi = 0; mi < 4; ++mi)
            #pragma unroll
            for (int ni = 0; ni < 4; ++ni)
                acc[mi][ni] = __builtin_amdgcn_mfma_f32_16x16x32_bf16(
                    af[mi], bf[ni], acc[mi][ni], 0, 0, 0);
        __syncthreads();
    }

    int lq = l >> 4;
    #pragma unroll
    for (int ni = 0; ni < 4; ++ni) {
        int col = n0 + wn * 64 + ni * 16 + lrow;
        if (col >= realN) continue;
        float bv = bias ? bias[col] : 0.f;
        #pragma unroll
        for (int mi = 0; mi < 4; ++mi) {
            int rbase = r0 + wm * 64 + mi * 16 + lq * 4;
            floatx4 v = acc[mi][ni];
            #pragma unroll
            for (int r = 0; r < 4; ++r) {
                int row = rbase + r;
                if (row < realM) Out[(long)row * ldo + col] = v[r] + bv;
            }
        }
    }
}

// ---------------------------------------------------------------------------
// K3 (register version): per edge, thread c streams n=0..24:
//   one coalesced global load, scale by reg-held rad[l], accumulate 19
//   register accs with broadcast LDS reads of pre-permuted Wigner rows.
__global__ __launch_bounds__(384) void k_build_mp(
    const float* __restrict__ x, const float* __restrict__ ef, const float* __restrict__ wgn,
    const float* __restrict__ wrad, const int* __restrict__ eidx,
    __hip_bfloat16* __restrict__ A0, __hip_bfloat16* __restrict__ A1,
    __hip_bfloat16* __restrict__ A2, int e0, int E)
{
    __shared__ float swig[475];   // 19 permuted rows x 25
    int tid = threadIdx.x;
    int le = blockIdx.x;
    long e = e0 + le;
    int src = eidx[e], tgt = eidx[E + e];

    for (int i = tid; i < 475; i += 384) {
        int j = i / 25, n = i - j * 25;
        swig[i] = wgn[e * 625 + c_MASKP[j] * 25 + n];
    }

    int c = tid;  // 0..383 (wave-uniform branch: waves 0-1 src, 2-3 tgt, 4-5 ef)
    float rad[5];
    #pragma unroll
    for (int l = 0; l < 5; ++l) rad[l] = wrad[(long)le * 1920 + l * 384 + c];

    const float* base;
    if (c < 128)      base = x  + (long)src * 3200 + c;
    else if (c < 256) base = x  + (long)tgt * 3200 + (c - 128);
    else              base = ef + e * 3200 + (c - 256);

    __syncthreads();

    float acc[19] = {};
    #pragma unroll
    for (int n = 0; n < 25; ++n) {
        float v = base[n * 128] * rad[c_LFULL[n]];
        #pragma unroll
        for (int j = 0; j < 19; ++j)
            acc[j] += swig[j * 25 + n] * v;
    }

    #pragma unroll
    for (int j = 0; j < 19; ++j) {
        __hip_bfloat16 hv = __float2bfloat16(acc[j]);
        if (j < 5)       A0[(long)le * 1920 + j * 384 + c] = hv;
        else if (j < 9)  A1[(long)(2 * le)     * 1536 + (j - 5)  * 384 + c] = hv;
        else if (j < 13) A1[(long)(2 * le + 1) * 1536 + (j - 9)  * 384 + c] = hv;
        else if (j < 16) A2[(long)(2 * le)     * 1152 + (j - 13) * 384 + c] = hv;
        else             A2[(long)(2 * le + 1) * 1152 + (j - 16) * 384 + c] = hv;
    }
}

// ---------------------------------------------------------------------------
// K5a: recombine + gate + transposed Wigner -> sful as split-bf16 rows.
// Row (e, l, ni) stored at sfl[(CE*l^2 + le*(2l+1) + ni)*192] as [hi|hi|lo].
__global__ __launch_bounds__(256) void k_combine_a(
    const float* __restrict__ wgn, const float* __restrict__ ym0,
    const float* __restrict__ ym1, const float* __restrict__ ym2,
    __hip_bfloat16* __restrict__ sfl, int e0, int CE)
{
    __shared__ float swig[475];   // 19 permuted rows x 25
    __shared__ float shl[1216];   // 19 x 64
    int tid = threadIdx.x;
    int le = blockIdx.x;
    long e = e0 + le;

    for (int i = tid; i < 475; i += 256) {
        int j = i / 25, n = i - j * 25;
        swig[i] = wgn[e * 625 + c_MASKP[j] * 25 + n];
    }

    const float* y0  = ym0 + (long)le * 576;
    const float* y1a = ym1 + (long)(2 * le) * 512;
    const float* y1b = ym1 + (long)(2 * le + 1) * 512;
    const float* y2a = ym2 + (long)(2 * le) * 384;
    const float* y2b = ym2 + (long)(2 * le + 1) * 384;

    for (int i = tid; i < 1216; i += 256) {
        int j = i >> 6, c = i & 63;
        float raw;
        if (j < 5)        raw = y0[256 + j * 64 + c];
        else if (j < 9)   { int k = (j - 5) * 64 + c;  raw = y1a[k] - y1b[256 + k]; }
        else if (j < 13)  { int k = (j - 9) * 64 + c;  raw = y1b[k] + y1a[256 + k]; }
        else if (j < 16)  { int k = (j - 13) * 64 + c; raw = y2a[k] - y2b[192 + k]; }
        else              { int k = (j - 16) * 64 + c; raw = y2b[k] + y2a[192 + k]; }
        float v;
        if (j == 0) v = raw * sigm_(raw);
        else        v = raw * sigm_(y0[c_GATEP[j] * 64 + c]);
        shl[i] = v;
    }
    __syncthreads();

    for (int i = tid; i < 1600; i += 256) {
        int n = i >> 6, c = i & 63;          // n uniform per wave -> swig broadcast
        float acc = 0.f;
        #pragma unroll
        for (int j = 0; j < 19; ++j) acc += swig[j * 25 + n] * shl[j * 64 + c];
        __hip_bfloat16 hi = __float2bfloat16(acc);
        __hip_bfloat16 lo = __float2bfloat16(acc - __bfloat162float(hi));
        int l = c_LFULL[n];
        int nb = l * l, cnt = 2 * l + 1, ni = n - nb;
        long row = (long)CE * nb + (long)le * cnt + ni;
        sfl[row * 192 + c]       = hi;
        sfl[row * 192 + 64 + c]  = hi;
        sfl[row * 192 + 128 + c] = lo;
    }
}

// ---------------------------------------------------------------------------
// K5b: merged projection GEMM over all 5 l-segments.
//   out[e,nb+ni,o] = sum_i sful[e,nb+ni,i] * pw[l][o,i]  (+pb[o] for l=0)
// A = sfl split rows (K=192), B = pwb (K=192). One tile row per block.
__global__ __launch_bounds__(256) void k_proj_gemm(
    const __hip_bfloat16* __restrict__ sfl,
    const __hip_bfloat16* __restrict__ pwb,
    const float* __restrict__ pb,
    float* __restrict__ out, int ec, int CE)
{
    __shared__ __align__(16) __hip_bfloat16 As[128 * 32];
    __shared__ __align__(16) __hip_bfloat16 Bs[128 * 32];
    int tid = threadIdx.x;
    int ln = tid & 63, w = tid >> 6;
    int wm = w & 1, wn = w >> 1;

    // locate l-segment (monotone scan, no break)
    int bid = blockIdx.x;
    int l = 0, base = 0;
    #pragma unroll
    for (int ll = 0; ll < 5; ++ll) {
        int tiles = (ec * (2 * ll + 1) + 127) >> 7;
        if (bid >= base + tiles) { base += tiles; l = ll + 1; }
    }
    if (l > 4) return;
    int cnt = 2 * l + 1, nb = l * l;
    int realM = ec * cnt;
    int r0 = (bid - base) * 128;

    const __hip_bfloat16* A = sfl + (long)CE * nb * 192;
    const __hip_bfloat16* B = pwb + l * 128 * 192;

    floatx4 acc[4][4] = {};

    int srow = w * 16 + (ln >> 2);
    int scol = (ln & 3) * 8;
    const __hip_bfloat16* Ag = A + (long)(r0 + srow) * 192 + scol;
    const __hip_bfloat16* Bg = B + (long)srow * 192 + scol;
    __hip_bfloat16* AsW = As + (w * 16) * 32;
    __hip_bfloat16* BsW = Bs + (w * 16) * 32;

    int lrow = ln & 15, lk = (ln >> 4) * 8;

    for (int kk = 0; kk < 192; kk += 32) {
        async16(Ag + kk, AsW);
        async16(Ag + (long)64 * 192 + kk, AsW + 64 * 32);
        async16(Bg + kk, BsW);
        async16(Bg + (long)64 * 192 + kk, BsW + 64 * 32);
        __syncthreads();
        bf16x8 af[4], bf[4];
        #pragma unroll
        for (int mi = 0; mi < 4; ++mi)
            af[mi] = *(const bf16x8*)&As[(wm * 64 + mi * 16 + lrow) * 32 + lk];
        #pragma unroll
        for (int ni = 0; ni < 4; ++ni)
            bf[ni] = *(const bf16x8*)&Bs[(wn * 64 + ni * 16 + lrow) * 32 + lk];
        #pragma unroll
        for (int mi = 0; mi < 4; ++mi)
            #pragma unroll
            for (int ni = 0; ni < 4; ++ni)
                acc[mi][ni] = __builtin_amdgcn_mfma_f32_16x16x32_bf16(
                    af[mi], bf[ni], acc[mi][ni], 0, 0, 0);
        __syncthreads();
    }

    int lq = ln >> 4;
    #pragma unroll
    for (int mi = 0; mi < 4; ++mi) {
        #pragma unroll
        for (int r = 0; r < 4; ++r) {
            int row = r0 + wm * 64 + mi * 16 + lq * 4 + r;
            if (row >= realM) continue;
            int e = row / cnt;
            int nn = nb + (row - e * cnt);
            float* op = out + (long)e * 3200 + (long)nn * 128;
            #pragma unroll
            for (int nib = 0; nib < 4; ++nib) {
                int col = wn * 64 + nib * 16 + lrow;
                float bv = (l == 0) ? pb[col] : 0.f;
                op[col] = acc[mi][nib][r] + bv;
            }
        }
    }
}

// ---------------------------------------------------------------------------
extern "C" void kernel_launch(void* const* d_in, const int* in_sizes, int n_in,
                              void* d_out, int out_size, void* d_ws, size_t ws_size,
                              hipStream_t stream)
{
    const float* x    = (const float*)d_in[0];
    const float* ef   = (const float*)d_in[1];
    const float* ed   = (const float*)d_in[2];
    const float* wgn  = (const float*)d_in[3];
    const float* se   = (const float*)d_in[4];
    const float* te   = (const float*)d_in[5];
    const float* w1   = (const float*)d_in[6];
    const float* b1   = (const float*)d_in[7];
    const float* g1   = (const float*)d_in[8];
    const float* bb1  = (const float*)d_in[9];
    const float* w2   = (const float*)d_in[10];
    const float* b2   = (const float*)d_in[11];
    const float* g2   = (const float*)d_in[12];
    const float* bb2  = (const float*)d_in[13];
    const float* w3   = (const float*)d_in[14];
    const float* b3   = (const float*)d_in[15];
    const float* wm0  = (const float*)d_in[16];
    const float* bm0  = (const float*)d_in[17];
    const float* wm1  = (const float*)d_in[18];
    const float* wm2  = (const float*)d_in[19];
    const float* pw   = (const float*)d_in[20];
    const float* pb   = (const float*)d_in[21];
    const int*   an   = (const int*)d_in[22];
    const int*   eidx = (const int*)d_in[23];
    float* out = (float*)d_out;
    char*  ws  = (char*)d_ws;

    const int E = in_sizes[23] / 2;           // 10000

    size_t off = 0;
    __hip_bfloat16* pwb = (__hip_bfloat16*)(ws + off); off += 5L * 128 * 192 * 2;
    __hip_bfloat16* Wb0 = (__hip_bfloat16*)(ws + off); off += 640L  * 1920 * 2;
    __hip_bfloat16* Wb1 = (__hip_bfloat16*)(ws + off); off += 512L  * 1536 * 2;
    __hip_bfloat16* Wb2 = (__hip_bfloat16*)(ws + off); off += 384L  * 1152 * 2;
    __hip_bfloat16* Wb3 = (__hip_bfloat16*)(ws + off); off += 1920L * 128  * 2;
    __hip_bfloat16* W1b = (__hip_bfloat16*)(ws + off); off += 128L  * 1152 * 2;
    __hip_bfloat16* W2b = (__hip_bfloat16*)(ws + off); off += 128L  * 384  * 2;
    size_t fixedBytes = off;

    // per-edge chunk bytes:
    //  h2b 256 + wrad 7680 + A0 3840 + A1 6144 + A2 4608 + y0 2304 + y1 4096
    //  + y2 3072 + sfl 9600 + xeb 2304 + h1 512 + h1s 768 + h2 512 = 45696
    long usable = (long)ws_size - (long)fixedBytes;
    long ceRaw = usable / 45696;
    long Epad = ((long)E + 127) & ~127L;
    long CE = ceRaw & ~127L;
    if (CE > Epad) CE = Epad;
    if (CE < 128) CE = 128;

    __hip_bfloat16* h2b = (__hip_bfloat16*)(ws + off); off += CE * 128 * 2;
    float* wrad = (float*)(ws + off);                  off += CE * 1920 * 4;
    __hip_bfloat16* A0 = (__hip_bfloat16*)(ws + off);  off += CE * 1920 * 2;
    __hip_bfloat16* A1 = (__hip_bfloat16*)(ws + off);  off += 2 * CE * 1536 * 2;
    __hip_bfloat16* A2 = (__hip_bfloat16*)(ws + off);  off += 2 * CE * 1152 * 2;
    float* y0 = (float*)(ws + off);                    off += CE * 576 * 4;
    float* y1 = (float*)(ws + off);                    off += 2 * CE * 512 * 4;
    float* y2 = (float*)(ws + off);                    off += 2 * CE * 384 * 4;
    __hip_bfloat16* sfl = (__hip_bfloat16*)(ws + off); off += CE * 25 * 192 * 2;
    __hip_bfloat16* xeb = (__hip_bfloat16*)(ws + off); off += CE * 1152 * 2;
    float* h1 = (float*)(ws + off);                    off += CE * 128 * 4;
    __hip_bfloat16* h1s = (__hip_bfloat16*)(ws + off); off += CE * 384 * 2;
    float* h2 = (float*)(ws + off);                    off += CE * 128 * 4;

    k_split_pw<<<160, 256, 0, stream>>>(pw, pwb);
    k_cvt_w<<<(640 * 1920 + 255) / 256, 256, 0, stream>>>(wm0 + 512L * 1920, Wb0, 576, 640, 1920);
    k_cvt_w<<<(512 * 1536 + 255) / 256, 256, 0, stream>>>(wm1, Wb1, 512, 512, 1536);
    k_cvt_w<<<(384 * 1152 + 255) / 256, 256, 0, stream>>>(wm2, Wb2, 384, 384, 1152);
    k_cvt_w<<<(1920 * 128 + 255) / 256, 256, 0, stream>>>(w3, Wb3, 1920, 1920, 128);
    k_cvt_w_split<<<(128 * 384 + 255) / 256, 256, 0, stream>>>(w1, W1b, 128, 384);
    k_cvt_w_split<<<(128 * 128 + 255) / 256, 256, 0, stream>>>(w2, W2b, 128, 128);

    for (int e0 = 0; e0 < E; e0 += (int)CE) {
        int ec = (E - e0 < (int)CE) ? (E - e0) : (int)CE;
        int Mp  = (ec + 127) & ~127;
        int Mp2 = (2 * ec + 127) & ~127;

        // --- radial MLP front as MFMA GEMMs ---
        k_build_xedge<<<dim3((ec * 384 + 255) / 256), 256, 0, stream>>>(
            ed, se, te, an, eidx, xeb, e0, ec, E);
        k_mfma_gemm<<<dim3(Mp / 128, 1), 256, 0, stream>>>(
            xeb, W1b, b1, h1, 128, ec, 128, 1152);
        k_ln_silu<<<dim3((ec + 3) / 4), 256, 0, stream>>>(h1, g1, bb1, h1s, ec, 1);
        k_mfma_gemm<<<dim3(Mp / 128, 1), 256, 0, stream>>>(
            h1s, W2b, b2, h2, 128, ec, 128, 384);
        k_ln_silu<<<dim3((ec + 3) / 4), 256, 0, stream>>>(h2, g2, bb2, h2b, ec, 0);

        k_mfma_gemm<<<dim3(Mp / 128, 1920 / 128), 256, 0, stream>>>(
            h2b, Wb3, b3, wrad, 1920, ec, 1920, 128);

        k_build_mp<<<dim3(ec), 384, 0, stream>>>(x, ef, wgn, wrad, eidx, A0, A1, A2, e0, E);

        k_mfma_gemm<<<dim3(Mp / 128, 640 / 128), 256, 0, stream>>>(
            A0, Wb0, bm0 + 512, y0, 576, ec, 576, 1920);
        k_mfma_gemm<<<dim3(Mp2 / 128, 512 / 128), 256, 0, stream>>>(
            A1, Wb1, (const float*)nullptr, y1, 512, 2 * ec, 512, 1536);
        k_mfma_gemm<<<dim3(Mp2 / 128, 384 / 128), 256, 0, stream>>>(
            A2, Wb2, (const float*)nullptr, y2, 384, 2 * ec, 384, 1152);

        k_combine_a<<<dim3(ec), 256, 0, stream>>>(wgn, y0, y1, y2, sfl, e0, (int)CE);

        int tilesTot = 0;
        for (int l = 0; l < 5; ++l) tilesTot += (ec * (2 * l + 1) + 127) >> 7;
        k_proj_gemm<<<dim3(tilesTot), 256, 0, stream>>>(
            sfl, pwb, pb, out + (long)e0 * 3200, ec, (int)CE);
    }
}

// Round 5
// 783.505 us; speedup vs baseline: 1.6096x; 1.1039x over previous
//
#include <hip/hip_runtime.h>
#include <hip/hip_bf16.h>
#include <stdint.h>

// Problem constants
//  L=4, MM=2, C=128, H=64, OUTC=128, EDGE_CH=128, X_EDGE=384, C3=384
//  NRED=19, NFULL=25, E=10000
//  Effective w_m0 rows 512..1087 (576 outs, padded to 640)

__constant__ int c_MASKP[19] = {0,2,6,12,20, 3,7,13,21, 1,5,11,19, 8,14,22, 4,10,18};
__constant__ int c_GATEP[19] = {-1,0,1,2,3, 0,1,2,3, 0,1,2,3, 1,2,3, 1,2,3};
__constant__ int c_LFULL[25] = {0,1,1,1,2,2,2,2,2,3,3,3,3,3,3,3,4,4,4,4,4,4,4,4,4};

__device__ __forceinline__ float sigm_(float x) { return 1.f / (1.f + __expf(-x)); }

typedef __attribute__((ext_vector_type(8))) __bf16 bf16x8;
typedef __attribute__((ext_vector_type(4))) float floatx4;

__device__ __forceinline__ void async16(const void* g, void* l) {
    __builtin_amdgcn_global_load_lds(
        (__attribute__((address_space(1))) void*)(g),
        (__attribute__((address_space(3))) void*)(l), 16, 0, 0);
}

// ---------------------------------------------------------------------------
// K0': split proj_w (5,128,64) fp32 -> pwb (5,128,192) bf16 as [hi | lo | hi]
// (pairs with A rows stored [hi | hi | lo] so that A.B = ah*bh + ah*bl + al*bh
//  ~ full fp32 product; dropped al*bl term is O(2^-18) relative)
__global__ void k_split_pw(const float* __restrict__ pw, __hip_bfloat16* __restrict__ pwb) {
    int d = blockIdx.x * 256 + threadIdx.x;
    if (d >= 40960) return;                 // 5*128*64
    int ll = d >> 13, rem = d & 8191;
    int o = rem >> 6, i = rem & 63;
    float v = pw[d];
    __hip_bfloat16 hi = __float2bfloat16(v);
    __hip_bfloat16 lo = __float2bfloat16(v - __bfloat162float(hi));
    long ob = (long)(ll * 128 + o) * 192;
    pwb[ob + i]       = hi;
    pwb[ob + 64 + i]  = lo;
    pwb[ob + 128 + i] = hi;
}

// ---------------------------------------------------------------------------
// Kc: fp32 weight [rows][K] -> bf16 [rowsPad][K], pad rows zero
__global__ void k_cvt_w(const float* __restrict__ W, __hip_bfloat16* __restrict__ out,
                        int rows, int rowsPad, int K) {
    long i = (long)blockIdx.x * 256 + threadIdx.x;
    if (i >= (long)rowsPad * K) return;
    int r = (int)(i / K);
    out[i] = __float2bfloat16(r < rows ? W[i] : 0.f);
}

// ---------------------------------------------------------------------------
// Kc': fp32 weight [rows][K] -> split bf16 [rows][3K] = [hi | lo | hi]
__global__ void k_cvt_w_split(const float* __restrict__ W, __hip_bfloat16* __restrict__ out,
                              int rows, int K) {
    long i = (long)blockIdx.x * 256 + threadIdx.x;
    if (i >= (long)rows * K) return;
    int r = (int)(i / K), k = (int)(i - (long)r * K);
    float v = W[i];
    __hip_bfloat16 hi = __float2bfloat16(v);
    __hip_bfloat16 lo = __float2bfloat16(v - __bfloat162float(hi));
    long ob = (long)r * 3 * K;
    out[ob + k]         = hi;
    out[ob + K + k]     = lo;
    out[ob + 2 * K + k] = hi;
}

// ---------------------------------------------------------------------------
// K1a: gather x_edge = [ed | se[an[src]] | te[an[tgt]]] -> split bf16 [CE][1152]
// rows stored [hi(384) | hi(384) | lo(384)]
__global__ __launch_bounds__(256) void k_build_xedge(
    const float* __restrict__ ed, const float* __restrict__ se, const float* __restrict__ te,
    const int* __restrict__ an, const int* __restrict__ eidx,
    __hip_bfloat16* __restrict__ xeb, int e0, int ec, int E)
{
    long i = (long)blockIdx.x * 256 + threadIdx.x;
    if (i >= (long)ec * 384) return;
    int le = (int)(i / 384), c = (int)(i - (long)le * 384);
    int e = e0 + le;
    float v;
    if (c < 128)       v = ed[(long)e * 128 + c];
    else if (c < 256)  { int s = eidx[e];     v = se[an[s] * 128 + (c - 128)]; }
    else               { int t = eidx[E + e]; v = te[an[t] * 128 + (c - 256)]; }
    __hip_bfloat16 hi = __float2bfloat16(v);
    __hip_bfloat16 lo = __float2bfloat16(v - __bfloat162float(hi));
    long ob = (long)le * 1152;
    xeb[ob + c]       = hi;
    xeb[ob + 384 + c] = hi;
    xeb[ob + 768 + c] = lo;
}

// ---------------------------------------------------------------------------
// K1b: per-row LayerNorm + SiLU on fp32 [ec][128].
// split==1: write split-bf16 rows [hi(128)|hi(128)|lo(128)] (ld 384)
// split==0: write plain bf16 rows (ld 128)
__global__ __launch_bounds__(256) void k_ln_silu(
    const float* __restrict__ H, const float* __restrict__ g, const float* __restrict__ bb,
    __hip_bfloat16* __restrict__ out, int ec, int split)
{
    int row = blockIdx.x * 4 + (threadIdx.x >> 6);
    if (row >= ec) return;
    int lane = threadIdx.x & 63;
    const float* hr = H + (long)row * 128;
    float v0 = hr[lane], v1 = hr[lane + 64];
    float s = v0 + v1, s2 = v0 * v0 + v1 * v1;
    #pragma unroll
    for (int o = 32; o >= 1; o >>= 1) {
        s  += __shfl_xor(s, o, 64);
        s2 += __shfl_xor(s2, o, 64);
    }
    float mu = s * (1.f / 128.f);
    float rs = rsqrtf(s2 * (1.f / 128.f) - mu * mu + 1e-5f);
    float a0 = (v0 - mu) * rs * g[lane]      + bb[lane];
    float a1 = (v1 - mu) * rs * g[lane + 64] + bb[lane + 64];
    a0 = a0 * sigm_(a0);
    a1 = a1 * sigm_(a1);
    if (split) {
        long ob = (long)row * 384;
        __hip_bfloat16 h0 = __float2bfloat16(a0);
        __hip_bfloat16 l0 = __float2bfloat16(a0 - __bfloat162float(h0));
        __hip_bfloat16 h1 = __float2bfloat16(a1);
        __hip_bfloat16 l1 = __float2bfloat16(a1 - __bfloat162float(h1));
        out[ob + lane]            = h0;
        out[ob + 128 + lane]      = h0;
        out[ob + 256 + lane]      = l0;
        out[ob + lane + 64]       = h1;
        out[ob + 128 + lane + 64] = h1;
        out[ob + 256 + lane + 64] = l1;
    } else {
        long ob = (long)row * 128;
        out[ob + lane]      = __float2bfloat16(a0);
        out[ob + lane + 64] = __float2bfloat16(a1);
    }
}

// ---------------------------------------------------------------------------
// MFMA GEMM (m97 structure): Out[r][o] = sum_k A[r][k]*B[o][k] (+bias[o])
// A: bf16 [Mpad][K], B: bf16 [Npad][K]; grid (Mpad/128, Npad/128); 256 thr.
__global__ __launch_bounds__(256) void k_mfma_gemm(
    const __hip_bfloat16* __restrict__ A,
    const __hip_bfloat16* __restrict__ B,
    const float* __restrict__ bias,
    float* __restrict__ Out, int ldo,
    int realM, int realN, int K)
{
    __shared__ __align__(16) __hip_bfloat16 As[128 * 32];
    __shared__ __align__(16) __hip_bfloat16 Bs[128 * 32];
    int tid = threadIdx.x;
    int l = tid & 63, w = tid >> 6;
    int r0 = blockIdx.x * 128, n0 = blockIdx.y * 128;
    int wm = w & 1, wn = w >> 1;

    floatx4 acc[4][4] = {};

    int srow = w * 16 + (l >> 2);
    int scol = (l & 3) * 8;
    const __hip_bfloat16* Ag = A + (long)(r0 + srow) * K + scol;
    const __hip_bfloat16* Bg = B + (long)(n0 + srow) * K + scol;
    __hip_bfloat16* AsW = As + (w * 16) * 32;
    __hip_bfloat16* BsW = Bs + (w * 16) * 32;

    int lrow = l & 15, lk = (l >> 4) * 8;

    for (int kk = 0; kk < K; kk += 32) {
        async16(Ag + kk, AsW);
        async16(Ag + (long)64 * K + kk, AsW + 64 * 32);
        async16(Bg + kk, BsW);
        async16(Bg + (long)64 * K + kk, BsW + 64 * 32);
        __syncthreads();
        bf16x8 af[4], bf[4];
        #pragma unroll
        for (int mi = 0; mi < 4; ++mi)
            af[mi] = *(const bf16x8*)&As[(wm * 64 + mi * 16 + lrow) * 32 + lk];
        #pragma unroll
        for (int ni = 0; ni < 4; ++ni)
            bf[ni] = *(const bf16x8*)&Bs[(wn * 64 + ni * 16 + lrow) * 32 + lk];
        #pragma unroll
        for (int mi = 0; mi < 4; ++mi)
            #pragma unroll
            for (int ni = 0; ni < 4; ++ni)
                acc[mi][ni] = __builtin_amdgcn_mfma_f32_16x16x32_bf16(
                    af[mi], bf[ni], acc[mi][ni], 0, 0, 0);
        __syncthreads();
    }

    int lq = l >> 4;
    #pragma unroll
    for (int ni = 0; ni < 4; ++ni) {
        int col = n0 + wn * 64 + ni * 16 + lrow;
        if (col >= realN) continue;
        float bv = bias ? bias[col] : 0.f;
        #pragma unroll
        for (int mi = 0; mi < 4; ++mi) {
            int rbase = r0 + wm * 64 + mi * 16 + lq * 4;
            floatx4 v = acc[mi][ni];
            #pragma unroll
            for (int r = 0; r < 4; ++r) {
                int row = rbase + r;
                if (row < realM) Out[(long)row * ldo + col] = v[r] + bv;
            }
        }
    }
}

// ---------------------------------------------------------------------------
// K3 v4: identical structure to the proven Round-2 kernel (384 thr, 1 edge/
// block, per-thread channel c, same writeback, same n-outer fp32 order).
// ONLY change: Wigner staged TRANSPOSED [25][20] (j-contiguous, 16B-aligned,
// j=19 zero pad) so the 19 per-n ds_read_b32 broadcasts become 5 ds_read_b128
// broadcasts: 475 -> 125 LDS instructions per thread.
__global__ __launch_bounds__(384) void k_build_mp(
    const float* __restrict__ x, const float* __restrict__ ef, const float* __restrict__ wgn,
    const float* __restrict__ wrad, const int* __restrict__ eidx,
    __hip_bfloat16* __restrict__ A0, __hip_bfloat16* __restrict__ A1,
    __hip_bfloat16* __restrict__ A2, int e0, int E)
{
    __shared__ __align__(16) float swig[512];   // [25][20] transposed, j padded
    int tid = threadIdx.x;
    int le = blockIdx.x;
    long e = e0 + le;
    int src = eidx[e], tgt = eidx[E + e];

    for (int i = tid; i < 500; i += 384) {
        int n = i / 20, j = i - n * 20;
        swig[i] = (j < 19) ? wgn[e * 625 + c_MASKP[j] * 25 + n] : 0.f;
    }

    int c = tid;  // 0..383 (wave-uniform branch: waves 0-1 src, 2-3 tgt, 4-5 ef)
    float rad[5];
    #pragma unroll
    for (int l = 0; l < 5; ++l) rad[l] = wrad[(long)le * 1920 + l * 384 + c];

    const float* base;
    if (c < 128)      base = x  + (long)src * 3200 + c;
    else if (c < 256) base = x  + (long)tgt * 3200 + (c - 128);
    else              base = ef + e * 3200 + (c - 256);

    __syncthreads();
    const float4* sw = (const float4*)swig;

    float acc[20] = {};
    #pragma unroll
    for (int n = 0; n < 25; ++n) {
        float v = base[n * 128] * rad[c_LFULL[n]];
        #pragma unroll
        for (int q = 0; q < 5; ++q) {
            float4 wv = sw[n * 5 + q];
            acc[q * 4 + 0] += wv.x * v;
            acc[q * 4 + 1] += wv.y * v;
            acc[q * 4 + 2] += wv.z * v;
            acc[q * 4 + 3] += wv.w * v;
        }
    }

    #pragma unroll
    for (int j = 0; j < 19; ++j) {
        __hip_bfloat16 hv = __float2bfloat16(acc[j]);
        if (j < 5)       A0[(long)le * 1920 + j * 384 + c] = hv;
        else if (j < 9)  A1[(long)(2 * le)     * 1536 + (j - 5)  * 384 + c] = hv;
        else if (j < 13) A1[(long)(2 * le + 1) * 1536 + (j - 9)  * 384 + c] = hv;
        else if (j < 16) A2[(long)(2 * le)     * 1152 + (j - 13) * 384 + c] = hv;
        else             A2[(long)(2 * le + 1) * 1152 + (j - 16) * 384 + c] = hv;
    }
}

// ---------------------------------------------------------------------------
// K5a: recombine + gate + transposed Wigner -> sful as split-bf16 rows.
// Row (e, l, ni) stored at sfl[(CE*l^2 + le*(2l+1) + ni)*192] as [hi|hi|lo].
__global__ __launch_bounds__(256) void k_combine_a(
    const float* __restrict__ wgn, const float* __restrict__ ym0,
    const float* __restrict__ ym1, const float* __restrict__ ym2,
    __hip_bfloat16* __restrict__ sfl, int e0, int CE)
{
    __shared__ float swig[475];   // 19 permuted rows x 25
    __shared__ float shl[1216];   // 19 x 64
    int tid = threadIdx.x;
    int le = blockIdx.x;
    long e = e0 + le;

    for (int i = tid; i < 475; i += 256) {
        int j = i / 25, n = i - j * 25;
        swig[i] = wgn[e * 625 + c_MASKP[j] * 25 + n];
    }

    const float* y0  = ym0 + (long)le * 576;
    const float* y1a = ym1 + (long)(2 * le) * 512;
    const float* y1b = ym1 + (long)(2 * le + 1) * 512;
    const float* y2a = ym2 + (long)(2 * le) * 384;
    const float* y2b = ym2 + (long)(2 * le + 1) * 384;

    for (int i = tid; i < 1216; i += 256) {
        int j = i >> 6, c = i & 63;
        float raw;
        if (j < 5)        raw = y0[256 + j * 64 + c];
        else if (j < 9)   { int k = (j - 5) * 64 + c;  raw = y1a[k] - y1b[256 + k]; }
        else if (j < 13)  { int k = (j - 9) * 64 + c;  raw = y1b[k] + y1a[256 + k]; }
        else if (j < 16)  { int k = (j - 13) * 64 + c; raw = y2a[k] - y2b[192 + k]; }
        else              { int k = (j - 16) * 64 + c; raw = y2b[k] + y2a[192 + k]; }
        float v;
        if (j == 0) v = raw * sigm_(raw);
        else        v = raw * sigm_(y0[c_GATEP[j] * 64 + c]);
        shl[i] = v;
    }
    __syncthreads();

    for (int i = tid; i < 1600; i += 256) {
        int n = i >> 6, c = i & 63;          // n uniform per wave -> swig broadcast
        float acc = 0.f;
        #pragma unroll
        for (int j = 0; j < 19; ++j) acc += swig[j * 25 + n] * shl[j * 64 + c];
        __hip_bfloat16 hi = __float2bfloat16(acc);
        __hip_bfloat16 lo = __float2bfloat16(acc - __bfloat162float(hi));
        int l = c_LFULL[n];
        int nb = l * l, cnt = 2 * l + 1, ni = n - nb;
        long row = (long)CE * nb + (long)le * cnt + ni;
        sfl[row * 192 + c]       = hi;
        sfl[row * 192 + 64 + c]  = hi;
        sfl[row * 192 + 128 + c] = lo;
    }
}

// ---------------------------------------------------------------------------
// K5b: merged projection GEMM over all 5 l-segments.
//   out[e,nb+ni,o] = sum_i sful[e,nb+ni,i] * pw[l][o,i]  (+pb[o] for l=0)
// A = sfl split rows (K=192), B = pwb (K=192). One tile row per block.
__global__ __launch_bounds__(256) void k_proj_gemm(
    const __hip_bfloat16* __restrict__ sfl,
    const __hip_bfloat16* __restrict__ pwb,
    const float* __restrict__ pb,
    float* __restrict__ out, int ec, int CE)
{
    __shared__ __align__(16) __hip_bfloat16 As[128 * 32];
    __shared__ __align__(16) __hip_bfloat16 Bs[128 * 32];
    int tid = threadIdx.x;
    int ln = tid & 63, w = tid >> 6;
    int wm = w & 1, wn = w >> 1;

    // locate l-segment (monotone scan, no break)
    int bid = blockIdx.x;
    int l = 0, base = 0;
    #pragma unroll
    for (int ll = 0; ll < 5; ++ll) {
        int tiles = (ec * (2 * ll + 1) + 127) >> 7;
        if (bid >= base + tiles) { base += tiles; l = ll + 1; }
    }
    if (l > 4) return;
    int cnt = 2 * l + 1, nb = l * l;
    int realM = ec * cnt;
    int r0 = (bid - base) * 128;

    const __hip_bfloat16* A = sfl + (long)CE * nb * 192;
    const __hip_bfloat16* B = pwb + l * 128 * 192;

    floatx4 acc[4][4] = {};

    int srow = w * 16 + (ln >> 2);
    int scol = (ln & 3) * 8;
    const __hip_bfloat16* Ag = A + (long)(r0 + srow) * 192 + scol;
    const __hip_bfloat16* Bg = B + (long)srow * 192 + scol;
    __hip_bfloat16* AsW = As + (w * 16) * 32;
    __hip_bfloat16* BsW = Bs + (w * 16) * 32;

    int lrow = ln & 15, lk = (ln >> 4) * 8;

    for (int kk = 0; kk < 192; kk += 32) {
        async16(Ag + kk, AsW);
        async16(Ag + (long)64 * 192 + kk, AsW + 64 * 32);
        async16(Bg + kk, BsW);
        async16(Bg + (long)64 * 192 + kk, BsW + 64 * 32);
        __syncthreads();
        bf16x8 af[4], bf[4];
        #pragma unroll
        for (int mi = 0; mi < 4; ++mi)
            af[mi] = *(const bf16x8*)&As[(wm * 64 + mi * 16 + lrow) * 32 + lk];
        #pragma unroll
        for (int ni = 0; ni < 4; ++ni)
            bf[ni] = *(const bf16x8*)&Bs[(wn * 64 + ni * 16 + lrow) * 32 + lk];
        #pragma unroll
        for (int mi = 0; mi < 4; ++mi)
            #pragma unroll
            for (int ni = 0; ni < 4; ++ni)
                acc[mi][ni] = __builtin_amdgcn_mfma_f32_16x16x32_bf16(
                    af[mi], bf[ni], acc[mi][ni], 0, 0, 0);
        __syncthreads();
    }

    int lq = ln >> 4;
    #pragma unroll
    for (int mi = 0; mi < 4; ++mi) {
        #pragma unroll
        for (int r = 0; r < 4; ++r) {
            int row = r0 + wm * 64 + mi * 16 + lq * 4 + r;
            if (row >= realM) continue;
            int e = row / cnt;
            int nn = nb + (row - e * cnt);
            float* op = out + (long)e * 3200 + (long)nn * 128;
            #pragma unroll
            for (int nib = 0; nib < 4; ++nib) {
                int col = wn * 64 + nib * 16 + lrow;
                float bv = (l == 0) ? pb[col] : 0.f;
                op[col] = acc[mi][nib][r] + bv;
            }
        }
    }
}

// ---------------------------------------------------------------------------
extern "C" void kernel_launch(void* const* d_in, const int* in_sizes, int n_in,
                              void* d_out, int out_size, void* d_ws, size_t ws_size,
                              hipStream_t stream)
{
    const float* x    = (const float*)d_in[0];
    const float* ef   = (const float*)d_in[1];
    const float* ed   = (const float*)d_in[2];
    const float* wgn  = (const float*)d_in[3];
    const float* se   = (const float*)d_in[4];
    const float* te   = (const float*)d_in[5];
    const float* w1   = (const float*)d_in[6];
    const float* b1   = (const float*)d_in[7];
    const float* g1   = (const float*)d_in[8];
    const float* bb1  = (const float*)d_in[9];
    const float* w2   = (const float*)d_in[10];
    const float* b2   = (const float*)d_in[11];
    const float* g2   = (const float*)d_in[12];
    const float* bb2  = (const float*)d_in[13];
    const float* w3   = (const float*)d_in[14];
    const float* b3   = (const float*)d_in[15];
    const float* wm0  = (const float*)d_in[16];
    const float* bm0  = (const float*)d_in[17];
    const float* wm1  = (const float*)d_in[18];
    const float* wm2  = (const float*)d_in[19];
    const float* pw   = (const float*)d_in[20];
    const float* pb   = (const float*)d_in[21];
    const int*   an   = (const int*)d_in[22];
    const int*   eidx = (const int*)d_in[23];
    float* out = (float*)d_out;
    char*  ws  = (char*)d_ws;

    const int E = in_sizes[23] / 2;           // 10000

    size_t off = 0;
    __hip_bfloat16* pwb = (__hip_bfloat16*)(ws + off); off += 5L * 128 * 192 * 2;
    __hip_bfloat16* Wb0 = (__hip_bfloat16*)(ws + off); off += 640L  * 1920 * 2;
    __hip_bfloat16* Wb1 = (__hip_bfloat16*)(ws + off); off += 512L  * 1536 * 2;
    __hip_bfloat16* Wb2 = (__hip_bfloat16*)(ws + off); off += 384L  * 1152 * 2;
    __hip_bfloat16* Wb3 = (__hip_bfloat16*)(ws + off); off += 1920L * 128  * 2;
    __hip_bfloat16* W1b = (__hip_bfloat16*)(ws + off); off += 128L  * 1152 * 2;
    __hip_bfloat16* W2b = (__hip_bfloat16*)(ws + off); off += 128L  * 384  * 2;
    size_t fixedBytes = off;

    // per-edge chunk bytes:
    //  h2b 256 + wrad 7680 + A0 3840 + A1 6144 + A2 4608 + y0 2304 + y1 4096
    //  + y2 3072 + sfl 9600 + xeb 2304 + h1 512 + h1s 768 + h2 512 = 45696
    long usable = (long)ws_size - (long)fixedBytes;
    long ceRaw = usable / 45696;
    long Epad = ((long)E + 127) & ~127L;
    long CE = ceRaw & ~127L;
    if (CE > Epad) CE = Epad;
    if (CE < 128) CE = 128;

    __hip_bfloat16* h2b = (__hip_bfloat16*)(ws + off); off += CE * 128 * 2;
    float* wrad = (float*)(ws + off);                  off += CE * 1920 * 4;
    __hip_bfloat16* A0 = (__hip_bfloat16*)(ws + off);  off += CE * 1920 * 2;
    __hip_bfloat16* A1 = (__hip_bfloat16*)(ws + off);  off += 2 * CE * 1536 * 2;
    __hip_bfloat16* A2 = (__hip_bfloat16*)(ws + off);  off += 2 * CE * 1152 * 2;
    float* y0 = (float*)(ws + off);                    off += CE * 576 * 4;
    float* y1 = (float*)(ws + off);                    off += 2 * CE * 512 * 4;
    float* y2 = (float*)(ws + off);                    off += 2 * CE * 384 * 4;
    __hip_bfloat16* sfl = (__hip_bfloat16*)(ws + off); off += CE * 25 * 192 * 2;
    __hip_bfloat16* xeb = (__hip_bfloat16*)(ws + off); off += CE * 1152 * 2;
    float* h1 = (float*)(ws + off);                    off += CE * 128 * 4;
    __hip_bfloat16* h1s = (__hip_bfloat16*)(ws + off); off += CE * 384 * 2;
    float* h2 = (float*)(ws + off);                    off += CE * 128 * 4;

    k_split_pw<<<160, 256, 0, stream>>>(pw, pwb);
    k_cvt_w<<<(640 * 1920 + 255) / 256, 256, 0, stream>>>(wm0 + 512L * 1920, Wb0, 576, 640, 1920);
    k_cvt_w<<<(512 * 1536 + 255) / 256, 256, 0, stream>>>(wm1, Wb1, 512, 512, 1536);
    k_cvt_w<<<(384 * 1152 + 255) / 256, 256, 0, stream>>>(wm2, Wb2, 384, 384, 1152);
    k_cvt_w<<<(1920 * 128 + 255) / 256, 256, 0, stream>>>(w3, Wb3, 1920, 1920, 128);
    k_cvt_w_split<<<(128 * 384 + 255) / 256, 256, 0, stream>>>(w1, W1b, 128, 384);
    k_cvt_w_split<<<(128 * 128 + 255) / 256, 256, 0, stream>>>(w2, W2b, 128, 128);

    for (int e0 = 0; e0 < E; e0 += (int)CE) {
        int ec = (E - e0 < (int)CE) ? (E - e0) : (int)CE;
        int Mp  = (ec + 127) & ~127;
        int Mp2 = (2 * ec + 127) & ~127;

        // --- radial MLP front as MFMA GEMMs ---
        k_build_xedge<<<dim3((ec * 384 + 255) / 256), 256, 0, stream>>>(
            ed, se, te, an, eidx, xeb, e0, ec, E);
        k_mfma_gemm<<<dim3(Mp / 128, 1), 256, 0, stream>>>(
            xeb, W1b, b1, h1, 128, ec, 128, 1152);
        k_ln_silu<<<dim3((ec + 3) / 4), 256, 0, stream>>>(h1, g1, bb1, h1s, ec, 1);
        k_mfma_gemm<<<dim3(Mp / 128, 1), 256, 0, stream>>>(
            h1s, W2b, b2, h2, 128, ec, 128, 384);
        k_ln_silu<<<dim3((ec + 3) / 4), 256, 0, stream>>>(h2, g2, bb2, h2b, ec, 0);

        k_mfma_gemm<<<dim3(Mp / 128, 1920 / 128), 256, 0, stream>>>(
            h2b, Wb3, b3, wrad, 1920, ec, 1920, 128);

        k_build_mp<<<dim3(ec), 384, 0, stream>>>(
            x, ef, wgn, wrad, eidx, A0, A1, A2, e0, E);

        k_mfma_gemm<<<dim3(Mp / 128, 640 / 128), 256, 0, stream>>>(
            A0, Wb0, bm0 + 512, y0, 576, ec, 576, 1920);
        k_mfma_gemm<<<dim3(Mp2 / 128, 512 / 128), 256, 0, stream>>>(
            A1, Wb1, (const float*)nullptr, y1, 512, 2 * ec, 512, 1536);
        k_mfma_gemm<<<dim3(Mp2 / 128, 384 / 128), 256, 0, stream>>>(
            A2, Wb2, (const float*)nullptr, y2, 384, 2 * ec, 384, 1152);

        k_combine_a<<<dim3(ec), 256, 0, stream>>>(wgn, y0, y1, y2, sfl, e0, (int)CE);

        int tilesTot = 0;
        for (int l = 0; l < 5; ++l) tilesTot += (ec * (2 * l + 1) + 127) >> 7;
        k_proj_gemm<<<dim3(tilesTot), 256, 0, stream>>>(
            sfl, pwb, pb, out + (long)e0 * 3200, ec, (int)CE);
    }
}

// Round 6
// 769.717 us; speedup vs baseline: 1.6385x; 1.0179x over previous
//
#include <hip/hip_runtime.h>
#include <hip/hip_bf16.h>
#include <stdint.h>

// Problem constants
//  L=4, MM=2, C=128, H=64, OUTC=128, EDGE_CH=128, X_EDGE=384, C3=384
//  NRED=19, NFULL=25, E=10000
//  Effective w_m0 rows 512..1087 (576 outs, padded to 640)

__constant__ int c_MASKP[19] = {0,2,6,12,20, 3,7,13,21, 1,5,11,19, 8,14,22, 4,10,18};
__constant__ int c_GATEP[19] = {-1,0,1,2,3, 0,1,2,3, 0,1,2,3, 1,2,3, 1,2,3};
__constant__ int c_LFULL[25] = {0,1,1,1,2,2,2,2,2,3,3,3,3,3,3,3,4,4,4,4,4,4,4,4,4};

__device__ __forceinline__ float sigm_(float x) { return 1.f / (1.f + __expf(-x)); }

typedef __attribute__((ext_vector_type(8))) __bf16 bf16x8;
typedef __attribute__((ext_vector_type(4))) float floatx4;

__device__ __forceinline__ void async16(const void* g, void* l) {
    __builtin_amdgcn_global_load_lds(
        (__attribute__((address_space(1))) void*)(g),
        (__attribute__((address_space(3))) void*)(l), 16, 0, 0);
}

// ---------------------------------------------------------------------------
// K0': split proj_w (5,128,64) fp32 -> pwb (5,128,192) bf16 as [hi | lo | hi]
// (pairs with A rows stored [hi | hi | lo] so that A.B = ah*bh + ah*bl + al*bh
//  ~ full fp32 product; dropped al*bl term is O(2^-18) relative)
__global__ void k_split_pw(const float* __restrict__ pw, __hip_bfloat16* __restrict__ pwb) {
    int d = blockIdx.x * 256 + threadIdx.x;
    if (d >= 40960) return;                 // 5*128*64
    int ll = d >> 13, rem = d & 8191;
    int o = rem >> 6, i = rem & 63;
    float v = pw[d];
    __hip_bfloat16 hi = __float2bfloat16(v);
    __hip_bfloat16 lo = __float2bfloat16(v - __bfloat162float(hi));
    long ob = (long)(ll * 128 + o) * 192;
    pwb[ob + i]       = hi;
    pwb[ob + 64 + i]  = lo;
    pwb[ob + 128 + i] = hi;
}

// ---------------------------------------------------------------------------
// Kc: fp32 weight [rows][K] -> bf16 [rowsPad][K], pad rows zero
__global__ void k_cvt_w(const float* __restrict__ W, __hip_bfloat16* __restrict__ out,
                        int rows, int rowsPad, int K) {
    long i = (long)blockIdx.x * 256 + threadIdx.x;
    if (i >= (long)rowsPad * K) return;
    int r = (int)(i / K);
    out[i] = __float2bfloat16(r < rows ? W[i] : 0.f);
}

// ---------------------------------------------------------------------------
// Kc': fp32 weight [rows][K] -> split bf16 [rows][3K] = [hi | lo | hi]
__global__ void k_cvt_w_split(const float* __restrict__ W, __hip_bfloat16* __restrict__ out,
                              int rows, int K) {
    long i = (long)blockIdx.x * 256 + threadIdx.x;
    if (i >= (long)rows * K) return;
    int r = (int)(i / K), k = (int)(i - (long)r * K);
    float v = W[i];
    __hip_bfloat16 hi = __float2bfloat16(v);
    __hip_bfloat16 lo = __float2bfloat16(v - __bfloat162float(hi));
    long ob = (long)r * 3 * K;
    out[ob + k]         = hi;
    out[ob + K + k]     = lo;
    out[ob + 2 * K + k] = hi;
}

// ---------------------------------------------------------------------------
// K1a: gather x_edge = [ed | se[an[src]] | te[an[tgt]]] -> split bf16 [CE][1152]
// rows stored [hi(384) | hi(384) | lo(384)]
__global__ __launch_bounds__(256) void k_build_xedge(
    const float* __restrict__ ed, const float* __restrict__ se, const float* __restrict__ te,
    const int* __restrict__ an, const int* __restrict__ eidx,
    __hip_bfloat16* __restrict__ xeb, int e0, int ec, int E)
{
    long i = (long)blockIdx.x * 256 + threadIdx.x;
    if (i >= (long)ec * 384) return;
    int le = (int)(i / 384), c = (int)(i - (long)le * 384);
    int e = e0 + le;
    float v;
    if (c < 128)       v = ed[(long)e * 128 + c];
    else if (c < 256)  { int s = eidx[e];     v = se[an[s] * 128 + (c - 128)]; }
    else               { int t = eidx[E + e]; v = te[an[t] * 128 + (c - 256)]; }
    __hip_bfloat16 hi = __float2bfloat16(v);
    __hip_bfloat16 lo = __float2bfloat16(v - __bfloat162float(hi));
    long ob = (long)le * 1152;
    xeb[ob + c]       = hi;
    xeb[ob + 384 + c] = hi;
    xeb[ob + 768 + c] = lo;
}

// ---------------------------------------------------------------------------
// K1b: per-row LayerNorm + SiLU on fp32 [ec][128].
// split==1: write split-bf16 rows [hi(128)|hi(128)|lo(128)] (ld 384)
// split==0: write plain bf16 rows (ld 128)
__global__ __launch_bounds__(256) void k_ln_silu(
    const float* __restrict__ H, const float* __restrict__ g, const float* __restrict__ bb,
    __hip_bfloat16* __restrict__ out, int ec, int split)
{
    int row = blockIdx.x * 4 + (threadIdx.x >> 6);
    if (row >= ec) return;
    int lane = threadIdx.x & 63;
    const float* hr = H + (long)row * 128;
    float v0 = hr[lane], v1 = hr[lane + 64];
    float s = v0 + v1, s2 = v0 * v0 + v1 * v1;
    #pragma unroll
    for (int o = 32; o >= 1; o >>= 1) {
        s  += __shfl_xor(s, o, 64);
        s2 += __shfl_xor(s2, o, 64);
    }
    float mu = s * (1.f / 128.f);
    float rs = rsqrtf(s2 * (1.f / 128.f) - mu * mu + 1e-5f);
    float a0 = (v0 - mu) * rs * g[lane]      + bb[lane];
    float a1 = (v1 - mu) * rs * g[lane + 64] + bb[lane + 64];
    a0 = a0 * sigm_(a0);
    a1 = a1 * sigm_(a1);
    if (split) {
        long ob = (long)row * 384;
        __hip_bfloat16 h0 = __float2bfloat16(a0);
        __hip_bfloat16 l0 = __float2bfloat16(a0 - __bfloat162float(h0));
        __hip_bfloat16 h1 = __float2bfloat16(a1);
        __hip_bfloat16 l1 = __float2bfloat16(a1 - __bfloat162float(h1));
        out[ob + lane]            = h0;
        out[ob + 128 + lane]      = h0;
        out[ob + 256 + lane]      = l0;
        out[ob + lane + 64]       = h1;
        out[ob + 128 + lane + 64] = h1;
        out[ob + 256 + lane + 64] = l1;
    } else {
        long ob = (long)row * 128;
        out[ob + lane]      = __float2bfloat16(a0);
        out[ob + lane + 64] = __float2bfloat16(a1);
    }
}

// ---------------------------------------------------------------------------
// MFMA GEMM (m97 structure): Out[r][o] = sum_k A[r][k]*B[o][k] (+bias[o])
// A: bf16 [Mpad][K], B: bf16 [Npad][K]; grid (Mpad/128, Npad/128); 256 thr.
__global__ __launch_bounds__(256) void k_mfma_gemm(
    const __hip_bfloat16* __restrict__ A,
    const __hip_bfloat16* __restrict__ B,
    const float* __restrict__ bias,
    float* __restrict__ Out, int ldo,
    int realM, int realN, int K)
{
    __shared__ __align__(16) __hip_bfloat16 As[128 * 32];
    __shared__ __align__(16) __hip_bfloat16 Bs[128 * 32];
    int tid = threadIdx.x;
    int l = tid & 63, w = tid >> 6;
    int r0 = blockIdx.x * 128, n0 = blockIdx.y * 128;
    int wm = w & 1, wn = w >> 1;

    floatx4 acc[4][4] = {};

    int srow = w * 16 + (l >> 2);
    int scol = (l & 3) * 8;
    const __hip_bfloat16* Ag = A + (long)(r0 + srow) * K + scol;
    const __hip_bfloat16* Bg = B + (long)(n0 + srow) * K + scol;
    __hip_bfloat16* AsW = As + (w * 16) * 32;
    __hip_bfloat16* BsW = Bs + (w * 16) * 32;

    int lrow = l & 15, lk = (l >> 4) * 8;

    for (int kk = 0; kk < K; kk += 32) {
        async16(Ag + kk, AsW);
        async16(Ag + (long)64 * K + kk, AsW + 64 * 32);
        async16(Bg + kk, BsW);
        async16(Bg + (long)64 * K + kk, BsW + 64 * 32);
        __syncthreads();
        bf16x8 af[4], bf[4];
        #pragma unroll
        for (int mi = 0; mi < 4; ++mi)
            af[mi] = *(const bf16x8*)&As[(wm * 64 + mi * 16 + lrow) * 32 + lk];
        #pragma unroll
        for (int ni = 0; ni < 4; ++ni)
            bf[ni] = *(const bf16x8*)&Bs[(wn * 64 + ni * 16 + lrow) * 32 + lk];
        #pragma unroll
        for (int mi = 0; mi < 4; ++mi)
            #pragma unroll
            for (int ni = 0; ni < 4; ++ni)
                acc[mi][ni] = __builtin_amdgcn_mfma_f32_16x16x32_bf16(
                    af[mi], bf[ni], acc[mi][ni], 0, 0, 0);
        __syncthreads();
    }

    int lq = l >> 4;
    #pragma unroll
    for (int ni = 0; ni < 4; ++ni) {
        int col = n0 + wn * 64 + ni * 16 + lrow;
        if (col >= realN) continue;
        float bv = bias ? bias[col] : 0.f;
        #pragma unroll
        for (int mi = 0; mi < 4; ++mi) {
            int rbase = r0 + wm * 64 + mi * 16 + lq * 4;
            floatx4 v = acc[mi][ni];
            #pragma unroll
            for (int r = 0; r < 4; ++r) {
                int row = rbase + r;
                if (row < realM) Out[(long)row * ldo + col] = v[r] + bv;
            }
        }
    }
}

// ---------------------------------------------------------------------------
// K3 v5: v4 structure (384 thr, 1 edge/block, transposed [25][20] Wigner,
// 5 ds_read_b128 broadcasts per n) + REGISTER PRELOAD of all 25 global
// values before the FMA loop. v4's VGPR_Count=32 forced load-use serial-
// ization; static-index vals[25] lifts all 25 loads into flight (~64 VGPR,
// still 8 waves/SIMD). Same n-outer j-inner fp32 order -> bit-identical.
__global__ __launch_bounds__(384) void k_build_mp(
    const float* __restrict__ x, const float* __restrict__ ef, const float* __restrict__ wgn,
    const float* __restrict__ wrad, const int* __restrict__ eidx,
    __hip_bfloat16* __restrict__ A0, __hip_bfloat16* __restrict__ A1,
    __hip_bfloat16* __restrict__ A2, int e0, int E)
{
    __shared__ __align__(16) float swig[512];   // [25][20] transposed, j padded
    int tid = threadIdx.x;
    int le = blockIdx.x;
    long e = e0 + le;
    int src = eidx[e], tgt = eidx[E + e];

    for (int i = tid; i < 500; i += 384) {
        int n = i / 20, j = i - n * 20;
        swig[i] = (j < 19) ? wgn[e * 625 + c_MASKP[j] * 25 + n] : 0.f;
    }

    int c = tid;  // 0..383 (wave-uniform branch: waves 0-1 src, 2-3 tgt, 4-5 ef)
    const float* base;
    if (c < 128)      base = x  + (long)src * 3200 + c;
    else if (c < 256) base = x  + (long)tgt * 3200 + (c - 128);
    else              base = ef + e * 3200 + (c - 256);

    // preload: 25 independent strided loads + 5 rad loads all in flight
    float vals[25];
    #pragma unroll
    for (int n = 0; n < 25; ++n) vals[n] = base[n * 128];
    float rad[5];
    #pragma unroll
    for (int l = 0; l < 5; ++l) rad[l] = wrad[(long)le * 1920 + l * 384 + c];
    #pragma unroll
    for (int n = 0; n < 25; ++n) vals[n] *= rad[c_LFULL[n]];

    __syncthreads();
    const float4* sw = (const float4*)swig;

    float acc[20] = {};
    #pragma unroll
    for (int n = 0; n < 25; ++n) {
        float v = vals[n];
        #pragma unroll
        for (int q = 0; q < 5; ++q) {
            float4 wv = sw[n * 5 + q];
            acc[q * 4 + 0] += wv.x * v;
            acc[q * 4 + 1] += wv.y * v;
            acc[q * 4 + 2] += wv.z * v;
            acc[q * 4 + 3] += wv.w * v;
        }
    }

    #pragma unroll
    for (int j = 0; j < 19; ++j) {
        __hip_bfloat16 hv = __float2bfloat16(acc[j]);
        if (j < 5)       A0[(long)le * 1920 + j * 384 + c] = hv;
        else if (j < 9)  A1[(long)(2 * le)     * 1536 + (j - 5)  * 384 + c] = hv;
        else if (j < 13) A1[(long)(2 * le + 1) * 1536 + (j - 9)  * 384 + c] = hv;
        else if (j < 16) A2[(long)(2 * le)     * 1152 + (j - 13) * 384 + c] = hv;
        else             A2[(long)(2 * le + 1) * 1152 + (j - 16) * 384 + c] = hv;
    }
}

// ---------------------------------------------------------------------------
// K5a v2: recombine + gate + transposed Wigner -> sful as split-bf16 rows.
// Wigner staged TRANSPOSED [25][20] (same trick as k_build_mp): the j-sum
// reads 5 float4 broadcasts instead of 19 stride-25 ds_read_b32.
// j-order preserved (0..18) -> bit-identical fp32 sum.
__global__ __launch_bounds__(256) void k_combine_a(
    const float* __restrict__ wgn, const float* __restrict__ ym0,
    const float* __restrict__ ym1, const float* __restrict__ ym2,
    __hip_bfloat16* __restrict__ sfl, int e0, int CE)
{
    __shared__ __align__(16) float swig[512];   // [25][20] transposed, j padded
    __shared__ float shl[1216];   // 19 x 64
    int tid = threadIdx.x;
    int le = blockIdx.x;
    long e = e0 + le;

    for (int i = tid; i < 500; i += 256) {
        int n = i / 20, j = i - n * 20;
        swig[i] = (j < 19) ? wgn[e * 625 + c_MASKP[j] * 25 + n] : 0.f;
    }

    const float* y0  = ym0 + (long)le * 576;
    const float* y1a = ym1 + (long)(2 * le) * 512;
    const float* y1b = ym1 + (long)(2 * le + 1) * 512;
    const float* y2a = ym2 + (long)(2 * le) * 384;
    const float* y2b = ym2 + (long)(2 * le + 1) * 384;

    for (int i = tid; i < 1216; i += 256) {
        int j = i >> 6, c = i & 63;
        float raw;
        if (j < 5)        raw = y0[256 + j * 64 + c];
        else if (j < 9)   { int k = (j - 5) * 64 + c;  raw = y1a[k] - y1b[256 + k]; }
        else if (j < 13)  { int k = (j - 9) * 64 + c;  raw = y1b[k] + y1a[256 + k]; }
        else if (j < 16)  { int k = (j - 13) * 64 + c; raw = y2a[k] - y2b[192 + k]; }
        else              { int k = (j - 16) * 64 + c; raw = y2b[k] + y2a[192 + k]; }
        float v;
        if (j == 0) v = raw * sigm_(raw);
        else        v = raw * sigm_(y0[c_GATEP[j] * 64 + c]);
        shl[i] = v;
    }
    __syncthreads();

    for (int i = tid; i < 1600; i += 256) {
        int n = i >> 6, c = i & 63;          // n uniform per wave -> swig broadcast
        const float4* sw = (const float4*)swig + n * 5;
        float acc = 0.f;
        float4 w0 = sw[0], w1 = sw[1], w2 = sw[2], w3 = sw[3], w4 = sw[4];
        acc += w0.x * shl[ 0 * 64 + c];
        acc += w0.y * shl[ 1 * 64 + c];
        acc += w0.z * shl[ 2 * 64 + c];
        acc += w0.w * shl[ 3 * 64 + c];
        acc += w1.x * shl[ 4 * 64 + c];
        acc += w1.y * shl[ 5 * 64 + c];
        acc += w1.z * shl[ 6 * 64 + c];
        acc += w1.w * shl[ 7 * 64 + c];
        acc += w2.x * shl[ 8 * 64 + c];
        acc += w2.y * shl[ 9 * 64 + c];
        acc += w2.z * shl[10 * 64 + c];
        acc += w2.w * shl[11 * 64 + c];
        acc += w3.x * shl[12 * 64 + c];
        acc += w3.y * shl[13 * 64 + c];
        acc += w3.z * shl[14 * 64 + c];
        acc += w3.w * shl[15 * 64 + c];
        acc += w4.x * shl[16 * 64 + c];
        acc += w4.y * shl[17 * 64 + c];
        acc += w4.z * shl[18 * 64 + c];
        __hip_bfloat16 hi = __float2bfloat16(acc);
        __hip_bfloat16 lo = __float2bfloat16(acc - __bfloat162float(hi));
        int l = c_LFULL[n];
        int nb = l * l, cnt = 2 * l + 1, ni = n - nb;
        long row = (long)CE * nb + (long)le * cnt + ni;
        sfl[row * 192 + c]       = hi;
        sfl[row * 192 + 64 + c]  = hi;
        sfl[row * 192 + 128 + c] = lo;
    }
}

// ---------------------------------------------------------------------------
// K5b: merged projection GEMM over all 5 l-segments.
//   out[e,nb+ni,o] = sum_i sful[e,nb+ni,i] * pw[l][o,i]  (+pb[o] for l=0)
// A = sfl split rows (K=192), B = pwb (K=192). One tile row per block.
__global__ __launch_bounds__(256) void k_proj_gemm(
    const __hip_bfloat16* __restrict__ sfl,
    const __hip_bfloat16* __restrict__ pwb,
    const float* __restrict__ pb,
    float* __restrict__ out, int ec, int CE)
{
    __shared__ __align__(16) __hip_bfloat16 As[128 * 32];
    __shared__ __align__(16) __hip_bfloat16 Bs[128 * 32];
    int tid = threadIdx.x;
    int ln = tid & 63, w = tid >> 6;
    int wm = w & 1, wn = w >> 1;

    // locate l-segment (monotone scan, no break)
    int bid = blockIdx.x;
    int l = 0, base = 0;
    #pragma unroll
    for (int ll = 0; ll < 5; ++ll) {
        int tiles = (ec * (2 * ll + 1) + 127) >> 7;
        if (bid >= base + tiles) { base += tiles; l = ll + 1; }
    }
    if (l > 4) return;
    int cnt = 2 * l + 1, nb = l * l;
    int realM = ec * cnt;
    int r0 = (bid - base) * 128;

    const __hip_bfloat16* A = sfl + (long)CE * nb * 192;
    const __hip_bfloat16* B = pwb + l * 128 * 192;

    floatx4 acc[4][4] = {};

    int srow = w * 16 + (ln >> 2);
    int scol = (ln & 3) * 8;
    const __hip_bfloat16* Ag = A + (long)(r0 + srow) * 192 + scol;
    const __hip_bfloat16* Bg = B + (long)srow * 192 + scol;
    __hip_bfloat16* AsW = As + (w * 16) * 32;
    __hip_bfloat16* BsW = Bs + (w * 16) * 32;

    int lrow = ln & 15, lk = (ln >> 4) * 8;

    for (int kk = 0; kk < 192; kk += 32) {
        async16(Ag + kk, AsW);
        async16(Ag + (long)64 * 192 + kk, AsW + 64 * 32);
        async16(Bg + kk, BsW);
        async16(Bg + (long)64 * 192 + kk, BsW + 64 * 32);
        __syncthreads();
        bf16x8 af[4], bf[4];
        #pragma unroll
        for (int mi = 0; mi < 4; ++mi)
            af[mi] = *(const bf16x8*)&As[(wm * 64 + mi * 16 + lrow) * 32 + lk];
        #pragma unroll
        for (int ni = 0; ni < 4; ++ni)
            bf[ni] = *(const bf16x8*)&Bs[(wn * 64 + ni * 16 + lrow) * 32 + lk];
        #pragma unroll
        for (int mi = 0; mi < 4; ++mi)
            #pragma unroll
            for (int ni = 0; ni < 4; ++ni)
                acc[mi][ni] = __builtin_amdgcn_mfma_f32_16x16x32_bf16(
                    af[mi], bf[ni], acc[mi][ni], 0, 0, 0);
        __syncthreads();
    }

    int lq = ln >> 4;
    #pragma unroll
    for (int mi = 0; mi < 4; ++mi) {
        #pragma unroll
        for (int r = 0; r < 4; ++r) {
            int row = r0 + wm * 64 + mi * 16 + lq * 4 + r;
            if (row >= realM) continue;
            int e = row / cnt;
            int nn = nb + (row - e * cnt);
            float* op = out + (long)e * 3200 + (long)nn * 128;
            #pragma unroll
            for (int nib = 0; nib < 4; ++nib) {
                int col = wn * 64 + nib * 16 + lrow;
                float bv = (l == 0) ? pb[col] : 0.f;
                op[col] = acc[mi][nib][r] + bv;
            }
        }
    }
}

// ---------------------------------------------------------------------------
extern "C" void kernel_launch(void* const* d_in, const int* in_sizes, int n_in,
                              void* d_out, int out_size, void* d_ws, size_t ws_size,
                              hipStream_t stream)
{
    const float* x    = (const float*)d_in[0];
    const float* ef   = (const float*)d_in[1];
    const float* ed   = (const float*)d_in[2];
    const float* wgn  = (const float*)d_in[3];
    const float* se   = (const float*)d_in[4];
    const float* te   = (const float*)d_in[5];
    const float* w1   = (const float*)d_in[6];
    const float* b1   = (const float*)d_in[7];
    const float* g1   = (const float*)d_in[8];
    const float* bb1  = (const float*)d_in[9];
    const float* w2   = (const float*)d_in[10];
    const float* b2   = (const float*)d_in[11];
    const float* g2   = (const float*)d_in[12];
    const float* bb2  = (const float*)d_in[13];
    const float* w3   = (const float*)d_in[14];
    const float* b3   = (const float*)d_in[15];
    const float* wm0  = (const float*)d_in[16];
    const float* bm0  = (const float*)d_in[17];
    const float* wm1  = (const float*)d_in[18];
    const float* wm2  = (const float*)d_in[19];
    const float* pw   = (const float*)d_in[20];
    const float* pb   = (const float*)d_in[21];
    const int*   an   = (const int*)d_in[22];
    const int*   eidx = (const int*)d_in[23];
    float* out = (float*)d_out;
    char*  ws  = (char*)d_ws;

    const int E = in_sizes[23] / 2;           // 10000

    size_t off = 0;
    __hip_bfloat16* pwb = (__hip_bfloat16*)(ws + off); off += 5L * 128 * 192 * 2;
    __hip_bfloat16* Wb0 = (__hip_bfloat16*)(ws + off); off += 640L  * 1920 * 2;
    __hip_bfloat16* Wb1 = (__hip_bfloat16*)(ws + off); off += 512L  * 1536 * 2;
    __hip_bfloat16* Wb2 = (__hip_bfloat16*)(ws + off); off += 384L  * 1152 * 2;
    __hip_bfloat16* Wb3 = (__hip_bfloat16*)(ws + off); off += 1920L * 128  * 2;
    __hip_bfloat16* W1b = (__hip_bfloat16*)(ws + off); off += 128L  * 1152 * 2;
    __hip_bfloat16* W2b = (__hip_bfloat16*)(ws + off); off += 128L  * 384  * 2;
    size_t fixedBytes = off;

    // per-edge chunk bytes:
    //  h2b 256 + wrad 7680 + A0 3840 + A1 6144 + A2 4608 + y0 2304 + y1 4096
    //  + y2 3072 + sfl 9600 + xeb 2304 + h1 512 + h1s 768 + h2 512 = 45696
    long usable = (long)ws_size - (long)fixedBytes;
    long ceRaw = usable / 45696;
    long Epad = ((long)E + 127) & ~127L;
    long CE = ceRaw & ~127L;
    if (CE > Epad) CE = Epad;
    if (CE < 128) CE = 128;

    __hip_bfloat16* h2b = (__hip_bfloat16*)(ws + off); off += CE * 128 * 2;
    float* wrad = (float*)(ws + off);                  off += CE * 1920 * 4;
    __hip_bfloat16* A0 = (__hip_bfloat16*)(ws + off);  off += CE * 1920 * 2;
    __hip_bfloat16* A1 = (__hip_bfloat16*)(ws + off);  off += 2 * CE * 1536 * 2;
    __hip_bfloat16* A2 = (__hip_bfloat16*)(ws + off);  off += 2 * CE * 1152 * 2;
    float* y0 = (float*)(ws + off);                    off += CE * 576 * 4;
    float* y1 = (float*)(ws + off);                    off += 2 * CE * 512 * 4;
    float* y2 = (float*)(ws + off);                    off += 2 * CE * 384 * 4;
    __hip_bfloat16* sfl = (__hip_bfloat16*)(ws + off); off += CE * 25 * 192 * 2;
    __hip_bfloat16* xeb = (__hip_bfloat16*)(ws + off); off += CE * 1152 * 2;
    float* h1 = (float*)(ws + off);                    off += CE * 128 * 4;
    __hip_bfloat16* h1s = (__hip_bfloat16*)(ws + off); off += CE * 384 * 2;
    float* h2 = (float*)(ws + off);                    off += CE * 128 * 4;

    k_split_pw<<<160, 256, 0, stream>>>(pw, pwb);
    k_cvt_w<<<(640 * 1920 + 255) / 256, 256, 0, stream>>>(wm0 + 512L * 1920, Wb0, 576, 640, 1920);
    k_cvt_w<<<(512 * 1536 + 255) / 256, 256, 0, stream>>>(wm1, Wb1, 512, 512, 1536);
    k_cvt_w<<<(384 * 1152 + 255) / 256, 256, 0, stream>>>(wm2, Wb2, 384, 384, 1152);
    k_cvt_w<<<(1920 * 128 + 255) / 256, 256, 0, stream>>>(w3, Wb3, 1920, 1920, 128);
    k_cvt_w_split<<<(128 * 384 + 255) / 256, 256, 0, stream>>>(w1, W1b, 128, 384);
    k_cvt_w_split<<<(128 * 128 + 255) / 256, 256, 0, stream>>>(w2, W2b, 128, 128);

    for (int e0 = 0; e0 < E; e0 += (int)CE) {
        int ec = (E - e0 < (int)CE) ? (E - e0) : (int)CE;
        int Mp  = (ec + 127) & ~127;
        int Mp2 = (2 * ec + 127) & ~127;

        // --- radial MLP front as MFMA GEMMs ---
        k_build_xedge<<<dim3((ec * 384 + 255) / 256), 256, 0, stream>>>(
            ed, se, te, an, eidx, xeb, e0, ec, E);
        k_mfma_gemm<<<dim3(Mp / 128, 1), 256, 0, stream>>>(
            xeb, W1b, b1, h1, 128, ec, 128, 1152);
        k_ln_silu<<<dim3((ec + 3) / 4), 256, 0, stream>>>(h1, g1, bb1, h1s, ec, 1);
        k_mfma_gemm<<<dim3(Mp / 128, 1), 256, 0, stream>>>(
            h1s, W2b, b2, h2, 128, ec, 128, 384);
        k_ln_silu<<<dim3((ec + 3) / 4), 256, 0, stream>>>(h2, g2, bb2, h2b, ec, 0);

        k_mfma_gemm<<<dim3(Mp / 128, 1920 / 128), 256, 0, stream>>>(
            h2b, Wb3, b3, wrad, 1920, ec, 1920, 128);

        k_build_mp<<<dim3(ec), 384, 0, stream>>>(
            x, ef, wgn, wrad, eidx, A0, A1, A2, e0, E);

        k_mfma_gemm<<<dim3(Mp / 128, 640 / 128), 256, 0, stream>>>(
            A0, Wb0, bm0 + 512, y0, 576, ec, 576, 1920);
        k_mfma_gemm<<<dim3(Mp2 / 128, 512 / 128), 256, 0, stream>>>(
            A1, Wb1, (const float*)nullptr, y1, 512, 2 * ec, 512, 1536);
        k_mfma_gemm<<<dim3(Mp2 / 128, 384 / 128), 256, 0, stream>>>(
            A2, Wb2, (const float*)nullptr, y2, 384, 2 * ec, 384, 1152);

        k_combine_a<<<dim3(ec), 256, 0, stream>>>(wgn, y0, y1, y2, sfl, e0, (int)CE);

        int tilesTot = 0;
        for (int l = 0; l < 5; ++l) tilesTot += (ec * (2 * l + 1) + 127) >> 7;
        k_proj_gemm<<<dim3(tilesTot), 256, 0, stream>>>(
            sfl, pwb, pb, out + (long)e0 * 3200, ec, (int)CE);
    }
}

// Round 7
// 705.528 us; speedup vs baseline: 1.7875x; 1.0910x over previous
//
#include <hip/hip_runtime.h>
#include <hip/hip_bf16.h>
#include <stdint.h>

// Problem constants
//  L=4, MM=2, C=128, H=64, OUTC=128, EDGE_CH=128, X_EDGE=384, C3=384
//  NRED=19, NFULL=25, E=10000
//  Effective w_m0 rows 512..1087 (576 outs, padded to 640)

__constant__ int c_MASKP[19] = {0,2,6,12,20, 3,7,13,21, 1,5,11,19, 8,14,22, 4,10,18};
__constant__ int c_GATEP[19] = {-1,0,1,2,3, 0,1,2,3, 0,1,2,3, 1,2,3, 1,2,3};
__constant__ int c_LFULL[25] = {0,1,1,1,2,2,2,2,2,3,3,3,3,3,3,3,4,4,4,4,4,4,4,4,4};

__device__ __forceinline__ float sigm_(float x) { return 1.f / (1.f + __expf(-x)); }

typedef __attribute__((ext_vector_type(8))) __bf16 bf16x8;
typedef __attribute__((ext_vector_type(4))) float floatx4;

__device__ __forceinline__ void async16(const void* g, void* l) {
    __builtin_amdgcn_global_load_lds(
        (__attribute__((address_space(1))) void*)(g),
        (__attribute__((address_space(3))) void*)(l), 16, 0, 0);
}

// ---------------------------------------------------------------------------
// K0': split proj_w (5,128,64) fp32 -> pwb (5,128,192) bf16 as [hi | lo | hi]
__global__ void k_split_pw(const float* __restrict__ pw, __hip_bfloat16* __restrict__ pwb) {
    int d = blockIdx.x * 256 + threadIdx.x;
    if (d >= 40960) return;                 // 5*128*64
    int ll = d >> 13, rem = d & 8191;
    int o = rem >> 6, i = rem & 63;
    float v = pw[d];
    __hip_bfloat16 hi = __float2bfloat16(v);
    __hip_bfloat16 lo = __float2bfloat16(v - __bfloat162float(hi));
    long ob = (long)(ll * 128 + o) * 192;
    pwb[ob + i]       = hi;
    pwb[ob + 64 + i]  = lo;
    pwb[ob + 128 + i] = hi;
}

// ---------------------------------------------------------------------------
// Kc: fp32 weight [rows][K] -> bf16 [rowsPad][K], pad rows zero
__global__ void k_cvt_w(const float* __restrict__ W, __hip_bfloat16* __restrict__ out,
                        int rows, int rowsPad, int K) {
    long i = (long)blockIdx.x * 256 + threadIdx.x;
    if (i >= (long)rowsPad * K) return;
    int r = (int)(i / K);
    out[i] = __float2bfloat16(r < rows ? W[i] : 0.f);
}

// ---------------------------------------------------------------------------
// Kc': fp32 weight [rows][K] -> split bf16 [rows][3K] = [hi | lo | hi]
__global__ void k_cvt_w_split(const float* __restrict__ W, __hip_bfloat16* __restrict__ out,
                              int rows, int K) {
    long i = (long)blockIdx.x * 256 + threadIdx.x;
    if (i >= (long)rows * K) return;
    int r = (int)(i / K), k = (int)(i - (long)r * K);
    float v = W[i];
    __hip_bfloat16 hi = __float2bfloat16(v);
    __hip_bfloat16 lo = __float2bfloat16(v - __bfloat162float(hi));
    long ob = (long)r * 3 * K;
    out[ob + k]         = hi;
    out[ob + K + k]     = lo;
    out[ob + 2 * K + k] = hi;
}

// ---------------------------------------------------------------------------
// K1a: gather x_edge = [ed | se[an[src]] | te[an[tgt]]] -> split bf16 [CE][1152]
__global__ __launch_bounds__(256) void k_build_xedge(
    const float* __restrict__ ed, const float* __restrict__ se, const float* __restrict__ te,
    const int* __restrict__ an, const int* __restrict__ eidx,
    __hip_bfloat16* __restrict__ xeb, int e0, int ec, int E)
{
    long i = (long)blockIdx.x * 256 + threadIdx.x;
    if (i >= (long)ec * 384) return;
    int le = (int)(i / 384), c = (int)(i - (long)le * 384);
    int e = e0 + le;
    float v;
    if (c < 128)       v = ed[(long)e * 128 + c];
    else if (c < 256)  { int s = eidx[e];     v = se[an[s] * 128 + (c - 128)]; }
    else               { int t = eidx[E + e]; v = te[an[t] * 128 + (c - 256)]; }
    __hip_bfloat16 hi = __float2bfloat16(v);
    __hip_bfloat16 lo = __float2bfloat16(v - __bfloat162float(hi));
    long ob = (long)le * 1152;
    xeb[ob + c]       = hi;
    xeb[ob + 384 + c] = hi;
    xeb[ob + 768 + c] = lo;
}

// ---------------------------------------------------------------------------
// K1b: per-row LayerNorm + SiLU on fp32 [ec][128].
__global__ __launch_bounds__(256) void k_ln_silu(
    const float* __restrict__ H, const float* __restrict__ g, const float* __restrict__ bb,
    __hip_bfloat16* __restrict__ out, int ec, int split)
{
    int row = blockIdx.x * 4 + (threadIdx.x >> 6);
    if (row >= ec) return;
    int lane = threadIdx.x & 63;
    const float* hr = H + (long)row * 128;
    float v0 = hr[lane], v1 = hr[lane + 64];
    float s = v0 + v1, s2 = v0 * v0 + v1 * v1;
    #pragma unroll
    for (int o = 32; o >= 1; o >>= 1) {
        s  += __shfl_xor(s, o, 64);
        s2 += __shfl_xor(s2, o, 64);
    }
    float mu = s * (1.f / 128.f);
    float rs = rsqrtf(s2 * (1.f / 128.f) - mu * mu + 1e-5f);
    float a0 = (v0 - mu) * rs * g[lane]      + bb[lane];
    float a1 = (v1 - mu) * rs * g[lane + 64] + bb[lane + 64];
    a0 = a0 * sigm_(a0);
    a1 = a1 * sigm_(a1);
    if (split) {
        long ob = (long)row * 384;
        __hip_bfloat16 h0 = __float2bfloat16(a0);
        __hip_bfloat16 l0 = __float2bfloat16(a0 - __bfloat162float(h0));
        __hip_bfloat16 h1 = __float2bfloat16(a1);
        __hip_bfloat16 l1 = __float2bfloat16(a1 - __bfloat162float(h1));
        out[ob + lane]            = h0;
        out[ob + 128 + lane]      = h0;
        out[ob + 256 + lane]      = l0;
        out[ob + lane + 64]       = h1;
        out[ob + 128 + lane + 64] = h1;
        out[ob + 256 + lane + 64] = l1;
    } else {
        long ob = (long)row * 128;
        out[ob + lane]      = __float2bfloat16(a0);
        out[ob + lane + 64] = __float2bfloat16(a1);
    }
}

// ---------------------------------------------------------------------------
// Shared MFMA GEMM body (m97 structure): Out[r][o] = sum_k A[r][k]*B[o][k]
// As/Bs: LDS 128*32 bf16 each. r0/n0: tile origin. K runtime multiple of 32.
__device__ __forceinline__ void gemm_body(
    __hip_bfloat16* As, __hip_bfloat16* Bs,
    const __hip_bfloat16* A, const __hip_bfloat16* B,
    const float* bias, float* Out, int ldo,
    int realM, int realN, int K, int r0, int n0, int tid)
{
    int l = tid & 63, w = tid >> 6;
    int wm = w & 1, wn = w >> 1;

    floatx4 acc[4][4] = {};

    int srow = w * 16 + (l >> 2);
    int scol = (l & 3) * 8;
    const __hip_bfloat16* Ag = A + (long)(r0 + srow) * K + scol;
    const __hip_bfloat16* Bg = B + (long)(n0 + srow) * K + scol;
    __hip_bfloat16* AsW = As + (w * 16) * 32;
    __hip_bfloat16* BsW = Bs + (w * 16) * 32;

    int lrow = l & 15, lk = (l >> 4) * 8;

    for (int kk = 0; kk < K; kk += 32) {
        async16(Ag + kk, AsW);
        async16(Ag + (long)64 * K + kk, AsW + 64 * 32);
        async16(Bg + kk, BsW);
        async16(Bg + (long)64 * K + kk, BsW + 64 * 32);
        __syncthreads();
        bf16x8 af[4], bf[4];
        #pragma unroll
        for (int mi = 0; mi < 4; ++mi)
            af[mi] = *(const bf16x8*)&As[(wm * 64 + mi * 16 + lrow) * 32 + lk];
        #pragma unroll
        for (int ni = 0; ni < 4; ++ni)
            bf[ni] = *(const bf16x8*)&Bs[(wn * 64 + ni * 16 + lrow) * 32 + lk];
        #pragma unroll
        for (int mi = 0; mi < 4; ++mi)
            #pragma unroll
            for (int ni = 0; ni < 4; ++ni)
                acc[mi][ni] = __builtin_amdgcn_mfma_f32_16x16x32_bf16(
                    af[mi], bf[ni], acc[mi][ni], 0, 0, 0);
        __syncthreads();
    }

    int lq = l >> 4;
    #pragma unroll
    for (int ni = 0; ni < 4; ++ni) {
        int col = n0 + wn * 64 + ni * 16 + lrow;
        if (col >= realN) continue;
        float bv = bias ? bias[col] : 0.f;
        #pragma unroll
        for (int mi = 0; mi < 4; ++mi) {
            int rbase = r0 + wm * 64 + mi * 16 + lq * 4;
            floatx4 v = acc[mi][ni];
            #pragma unroll
            for (int r = 0; r < 4; ++r) {
                int row = rbase + r;
                if (row < realM) Out[(long)row * ldo + col] = v[r] + bv;
            }
        }
    }
}

// ---------------------------------------------------------------------------
// K2: standalone MFMA GEMM (grid (Mpad/128, Npad/128))
__global__ __launch_bounds__(256) void k_mfma_gemm(
    const __hip_bfloat16* __restrict__ A,
    const __hip_bfloat16* __restrict__ B,
    const float* __restrict__ bias,
    float* __restrict__ Out, int ldo,
    int realM, int realN, int K)
{
    __shared__ __align__(16) __hip_bfloat16 As[128 * 32];
    __shared__ __align__(16) __hip_bfloat16 Bs[128 * 32];
    gemm_body(As, Bs, A, B, bias, Out, ldo, realM, realN, K,
              blockIdx.x * 128, blockIdx.y * 128, threadIdx.x);
}

// ---------------------------------------------------------------------------
// K2': merged GEMM for the three independent y-GEMMs (y0, y1, y2).
// 1D grid, segment-decoded; overlaps the per-dispatch tails.
__global__ __launch_bounds__(256) void k_mfma_gemm3(
    const __hip_bfloat16* __restrict__ A0, const __hip_bfloat16* __restrict__ B0,
    const float* __restrict__ bias0, float* __restrict__ O0,
    const __hip_bfloat16* __restrict__ A1, const __hip_bfloat16* __restrict__ B1,
    float* __restrict__ O1,
    const __hip_bfloat16* __restrict__ A2, const __hip_bfloat16* __restrict__ B2,
    float* __restrict__ O2,
    int mt0, int mt1, int ec)
{
    __shared__ __align__(16) __hip_bfloat16 As[128 * 32];
    __shared__ __align__(16) __hip_bfloat16 Bs[128 * 32];
    int t = blockIdx.x;
    int s0 = mt0 * 5, s1 = mt1 * 4, s2 = mt1 * 3;
    if (t < s0) {
        gemm_body(As, Bs, A0, B0, bias0, O0, 576, ec, 576, 1920,
                  (t % mt0) * 128, (t / mt0) * 128, threadIdx.x);
    } else if (t < s0 + s1) {
        t -= s0;
        gemm_body(As, Bs, A1, B1, (const float*)nullptr, O1, 512, 2 * ec, 512, 1536,
                  (t % mt1) * 128, (t / mt1) * 128, threadIdx.x);
    } else if (t < s0 + s1 + s2) {
        t -= s0 + s1;
        gemm_body(As, Bs, A2, B2, (const float*)nullptr, O2, 384, 2 * ec, 384, 1152,
                  (t % mt1) * 128, (t / mt1) * 128, threadIdx.x);
    }
}

// ---------------------------------------------------------------------------
// K3 v6: v5 + ENFORCED preload (single asm keep-alive over all 30 loaded
// values -> compiler cannot re-sink the loads; one s_waitcnt instead of 30
// exposed latencies) + nontemporal loads for streamed ef/wrad (protects
// x's L2 residency; x is 12.8MB with ~20x reuse).
// Same n-outer j-inner fp32 order -> bit-identical.
__global__ __launch_bounds__(384) void k_build_mp(
    const float* __restrict__ x, const float* __restrict__ ef, const float* __restrict__ wgn,
    const float* __restrict__ wrad, const int* __restrict__ eidx,
    __hip_bfloat16* __restrict__ A0, __hip_bfloat16* __restrict__ A1,
    __hip_bfloat16* __restrict__ A2, int e0, int E)
{
    __shared__ __align__(16) float swig[512];   // [25][20] transposed, j padded
    int tid = threadIdx.x;
    int le = blockIdx.x;
    long e = e0 + le;
    int src = eidx[e], tgt = eidx[E + e];

    for (int i = tid; i < 500; i += 384) {
        int n = i / 20, j = i - n * 20;
        swig[i] = (j < 19) ? __builtin_nontemporal_load(
                                 &wgn[e * 625 + c_MASKP[j] * 25 + n]) : 0.f;
    }

    int c = tid;  // 0..383 (wave-uniform branch: waves 0-1 src, 2-3 tgt, 4-5 ef)
    float vals[25];
    if (c < 256) {
        const float* base = (c < 128) ? (x + (long)src * 3200 + c)
                                      : (x + (long)tgt * 3200 + (c - 128));
        #pragma unroll
        for (int n = 0; n < 25; ++n) vals[n] = base[n * 128];
    } else {
        const float* base = ef + e * 3200 + (c - 256);
        #pragma unroll
        for (int n = 0; n < 25; ++n)
            vals[n] = __builtin_nontemporal_load(&base[n * 128]);
    }
    float rad[5];
    #pragma unroll
    for (int l = 0; l < 5; ++l)
        rad[l] = __builtin_nontemporal_load(&wrad[(long)le * 1920 + l * 384 + c]);

    // force all 30 loads to be issued and live before consumption (rule #17)
    asm volatile("" ::
        "v"(vals[0]),  "v"(vals[1]),  "v"(vals[2]),  "v"(vals[3]),  "v"(vals[4]),
        "v"(vals[5]),  "v"(vals[6]),  "v"(vals[7]),  "v"(vals[8]),  "v"(vals[9]),
        "v"(vals[10]), "v"(vals[11]), "v"(vals[12]), "v"(vals[13]), "v"(vals[14]),
        "v"(vals[15]), "v"(vals[16]), "v"(vals[17]), "v"(vals[18]), "v"(vals[19]),
        "v"(vals[20]), "v"(vals[21]), "v"(vals[22]), "v"(vals[23]), "v"(vals[24]),
        "v"(rad[0]), "v"(rad[1]), "v"(rad[2]), "v"(rad[3]), "v"(rad[4]));

    #pragma unroll
    for (int n = 0; n < 25; ++n) vals[n] *= rad[c_LFULL[n]];

    __syncthreads();
    const float4* sw = (const float4*)swig;

    float acc[20] = {};
    #pragma unroll
    for (int n = 0; n < 25; ++n) {
        float v = vals[n];
        #pragma unroll
        for (int q = 0; q < 5; ++q) {
            float4 wv = sw[n * 5 + q];
            acc[q * 4 + 0] += wv.x * v;
            acc[q * 4 + 1] += wv.y * v;
            acc[q * 4 + 2] += wv.z * v;
            acc[q * 4 + 3] += wv.w * v;
        }
    }

    #pragma unroll
    for (int j = 0; j < 19; ++j) {
        __hip_bfloat16 hv = __float2bfloat16(acc[j]);
        if (j < 5)       A0[(long)le * 1920 + j * 384 + c] = hv;
        else if (j < 9)  A1[(long)(2 * le)     * 1536 + (j - 5)  * 384 + c] = hv;
        else if (j < 13) A1[(long)(2 * le + 1) * 1536 + (j - 9)  * 384 + c] = hv;
        else if (j < 16) A2[(long)(2 * le)     * 1152 + (j - 13) * 384 + c] = hv;
        else             A2[(long)(2 * le + 1) * 1152 + (j - 16) * 384 + c] = hv;
    }
}

// ---------------------------------------------------------------------------
// K5a v2: recombine + gate + transposed Wigner -> sful as split-bf16 rows.
__global__ __launch_bounds__(256) void k_combine_a(
    const float* __restrict__ wgn, const float* __restrict__ ym0,
    const float* __restrict__ ym1, const float* __restrict__ ym2,
    __hip_bfloat16* __restrict__ sfl, int e0, int CE)
{
    __shared__ __align__(16) float swig[512];   // [25][20] transposed, j padded
    __shared__ float shl[1216];   // 19 x 64
    int tid = threadIdx.x;
    int le = blockIdx.x;
    long e = e0 + le;

    for (int i = tid; i < 500; i += 256) {
        int n = i / 20, j = i - n * 20;
        swig[i] = (j < 19) ? __builtin_nontemporal_load(
                                 &wgn[e * 625 + c_MASKP[j] * 25 + n]) : 0.f;
    }

    const float* y0  = ym0 + (long)le * 576;
    const float* y1a = ym1 + (long)(2 * le) * 512;
    const float* y1b = ym1 + (long)(2 * le + 1) * 512;
    const float* y2a = ym2 + (long)(2 * le) * 384;
    const float* y2b = ym2 + (long)(2 * le + 1) * 384;

    for (int i = tid; i < 1216; i += 256) {
        int j = i >> 6, c = i & 63;
        float raw;
        if (j < 5)        raw = y0[256 + j * 64 + c];
        else if (j < 9)   { int k = (j - 5) * 64 + c;  raw = y1a[k] - y1b[256 + k]; }
        else if (j < 13)  { int k = (j - 9) * 64 + c;  raw = y1b[k] + y1a[256 + k]; }
        else if (j < 16)  { int k = (j - 13) * 64 + c; raw = y2a[k] - y2b[192 + k]; }
        else              { int k = (j - 16) * 64 + c; raw = y2b[k] + y2a[192 + k]; }
        float v;
        if (j == 0) v = raw * sigm_(raw);
        else        v = raw * sigm_(y0[c_GATEP[j] * 64 + c]);
        shl[i] = v;
    }
    __syncthreads();

    for (int i = tid; i < 1600; i += 256) {
        int n = i >> 6, c = i & 63;          // n uniform per wave -> swig broadcast
        const float4* sw = (const float4*)swig + n * 5;
        float acc = 0.f;
        float4 w0 = sw[0], w1 = sw[1], w2 = sw[2], w3 = sw[3], w4 = sw[4];
        acc += w0.x * shl[ 0 * 64 + c];
        acc += w0.y * shl[ 1 * 64 + c];
        acc += w0.z * shl[ 2 * 64 + c];
        acc += w0.w * shl[ 3 * 64 + c];
        acc += w1.x * shl[ 4 * 64 + c];
        acc += w1.y * shl[ 5 * 64 + c];
        acc += w1.z * shl[ 6 * 64 + c];
        acc += w1.w * shl[ 7 * 64 + c];
        acc += w2.x * shl[ 8 * 64 + c];
        acc += w2.y * shl[ 9 * 64 + c];
        acc += w2.z * shl[10 * 64 + c];
        acc += w2.w * shl[11 * 64 + c];
        acc += w3.x * shl[12 * 64 + c];
        acc += w3.y * shl[13 * 64 + c];
        acc += w3.z * shl[14 * 64 + c];
        acc += w3.w * shl[15 * 64 + c];
        acc += w4.x * shl[16 * 64 + c];
        acc += w4.y * shl[17 * 64 + c];
        acc += w4.z * shl[18 * 64 + c];
        __hip_bfloat16 hi = __float2bfloat16(acc);
        __hip_bfloat16 lo = __float2bfloat16(acc - __bfloat162float(hi));
        int l = c_LFULL[n];
        int nb = l * l, cnt = 2 * l + 1, ni = n - nb;
        long row = (long)CE * nb + (long)le * cnt + ni;
        sfl[row * 192 + c]       = hi;
        sfl[row * 192 + 64 + c]  = hi;
        sfl[row * 192 + 128 + c] = lo;
    }
}

// ---------------------------------------------------------------------------
// K5b: merged projection GEMM over all 5 l-segments.
__global__ __launch_bounds__(256) void k_proj_gemm(
    const __hip_bfloat16* __restrict__ sfl,
    const __hip_bfloat16* __restrict__ pwb,
    const float* __restrict__ pb,
    float* __restrict__ out, int ec, int CE)
{
    __shared__ __align__(16) __hip_bfloat16 As[128 * 32];
    __shared__ __align__(16) __hip_bfloat16 Bs[128 * 32];
    int tid = threadIdx.x;
    int ln = tid & 63, w = tid >> 6;
    int wm = w & 1, wn = w >> 1;

    // locate l-segment (monotone scan, no break)
    int bid = blockIdx.x;
    int l = 0, base = 0;
    #pragma unroll
    for (int ll = 0; ll < 5; ++ll) {
        int tiles = (ec * (2 * ll + 1) + 127) >> 7;
        if (bid >= base + tiles) { base += tiles; l = ll + 1; }
    }
    if (l > 4) return;
    int cnt = 2 * l + 1, nb = l * l;
    int realM = ec * cnt;
    int r0 = (bid - base) * 128;

    const __hip_bfloat16* A = sfl + (long)CE * nb * 192;
    const __hip_bfloat16* B = pwb + l * 128 * 192;

    floatx4 acc[4][4] = {};

    int srow = w * 16 + (ln >> 2);
    int scol = (ln & 3) * 8;
    const __hip_bfloat16* Ag = A + (long)(r0 + srow) * 192 + scol;
    const __hip_bfloat16* Bg = B + (long)srow * 192 + scol;
    __hip_bfloat16* AsW = As + (w * 16) * 32;
    __hip_bfloat16* BsW = Bs + (w * 16) * 32;

    int lrow = ln & 15, lk = (ln >> 4) * 8;

    for (int kk = 0; kk < 192; kk += 32) {
        async16(Ag + kk, AsW);
        async16(Ag + (long)64 * 192 + kk, AsW + 64 * 32);
        async16(Bg + kk, BsW);
        async16(Bg + (long)64 * 192 + kk, BsW + 64 * 32);
        __syncthreads();
        bf16x8 af[4], bf[4];
        #pragma unroll
        for (int mi = 0; mi < 4; ++mi)
            af[mi] = *(const bf16x8*)&As[(wm * 64 + mi * 16 + lrow) * 32 + lk];
        #pragma unroll
        for (int ni = 0; ni < 4; ++ni)
            bf[ni] = *(const bf16x8*)&Bs[(wn * 64 + ni * 16 + lrow) * 32 + lk];
        #pragma unroll
        for (int mi = 0; mi < 4; ++mi)
            #pragma unroll
            for (int ni = 0; ni < 4; ++ni)
                acc[mi][ni] = __builtin_amdgcn_mfma_f32_16x16x32_bf16(
                    af[mi], bf[ni], acc[mi][ni], 0, 0, 0);
        __syncthreads();
    }

    int lq = ln >> 4;
    #pragma unroll
    for (int mi = 0; mi < 4; ++mi) {
        #pragma unroll
        for (int r = 0; r < 4; ++r) {
            int row = r0 + wm * 64 + mi * 16 + lq * 4 + r;
            if (row >= realM) continue;
            int e = row / cnt;
            int nn = nb + (row - e * cnt);
            float* op = out + (long)e * 3200 + (long)nn * 128;
            #pragma unroll
            for (int nib = 0; nib < 4; ++nib) {
                int col = wn * 64 + nib * 16 + lrow;
                float bv = (l == 0) ? pb[col] : 0.f;
                op[col] = acc[mi][nib][r] + bv;
            }
        }
    }
}

// ---------------------------------------------------------------------------
extern "C" void kernel_launch(void* const* d_in, const int* in_sizes, int n_in,
                              void* d_out, int out_size, void* d_ws, size_t ws_size,
                              hipStream_t stream)
{
    const float* x    = (const float*)d_in[0];
    const float* ef   = (const float*)d_in[1];
    const float* ed   = (const float*)d_in[2];
    const float* wgn  = (const float*)d_in[3];
    const float* se   = (const float*)d_in[4];
    const float* te   = (const float*)d_in[5];
    const float* w1   = (const float*)d_in[6];
    const float* b1   = (const float*)d_in[7];
    const float* g1   = (const float*)d_in[8];
    const float* bb1  = (const float*)d_in[9];
    const float* w2   = (const float*)d_in[10];
    const float* b2   = (const float*)d_in[11];
    const float* g2   = (const float*)d_in[12];
    const float* bb2  = (const float*)d_in[13];
    const float* w3   = (const float*)d_in[14];
    const float* b3   = (const float*)d_in[15];
    const float* wm0  = (const float*)d_in[16];
    const float* bm0  = (const float*)d_in[17];
    const float* wm1  = (const float*)d_in[18];
    const float* wm2  = (const float*)d_in[19];
    const float* pw   = (const float*)d_in[20];
    const float* pb   = (const float*)d_in[21];
    const int*   an   = (const int*)d_in[22];
    const int*   eidx = (const int*)d_in[23];
    float* out = (float*)d_out;
    char*  ws  = (char*)d_ws;

    const int E = in_sizes[23] / 2;           // 10000

    size_t off = 0;
    __hip_bfloat16* pwb = (__hip_bfloat16*)(ws + off); off += 5L * 128 * 192 * 2;
    __hip_bfloat16* Wb0 = (__hip_bfloat16*)(ws + off); off += 640L  * 1920 * 2;
    __hip_bfloat16* Wb1 = (__hip_bfloat16*)(ws + off); off += 512L  * 1536 * 2;
    __hip_bfloat16* Wb2 = (__hip_bfloat16*)(ws + off); off += 384L  * 1152 * 2;
    __hip_bfloat16* Wb3 = (__hip_bfloat16*)(ws + off); off += 1920L * 128  * 2;
    __hip_bfloat16* W1b = (__hip_bfloat16*)(ws + off); off += 128L  * 1152 * 2;
    __hip_bfloat16* W2b = (__hip_bfloat16*)(ws + off); off += 128L  * 384  * 2;
    size_t fixedBytes = off;

    long usable = (long)ws_size - (long)fixedBytes;
    long ceRaw = usable / 45696;
    long Epad = ((long)E + 127) & ~127L;
    long CE = ceRaw & ~127L;
    if (CE > Epad) CE = Epad;
    if (CE < 128) CE = 128;

    __hip_bfloat16* h2b = (__hip_bfloat16*)(ws + off); off += CE * 128 * 2;
    float* wrad = (float*)(ws + off);                  off += CE * 1920 * 4;
    __hip_bfloat16* A0 = (__hip_bfloat16*)(ws + off);  off += CE * 1920 * 2;
    __hip_bfloat16* A1 = (__hip_bfloat16*)(ws + off);  off += 2 * CE * 1536 * 2;
    __hip_bfloat16* A2 = (__hip_bfloat16*)(ws + off);  off += 2 * CE * 1152 * 2;
    float* y0 = (float*)(ws + off);                    off += CE * 576 * 4;
    float* y1 = (float*)(ws + off);                    off += 2 * CE * 512 * 4;
    float* y2 = (float*)(ws + off);                    off += 2 * CE * 384 * 4;
    __hip_bfloat16* sfl = (__hip_bfloat16*)(ws + off); off += CE * 25 * 192 * 2;
    __hip_bfloat16* xeb = (__hip_bfloat16*)(ws + off); off += CE * 1152 * 2;
    float* h1 = (float*)(ws + off);                    off += CE * 128 * 4;
    __hip_bfloat16* h1s = (__hip_bfloat16*)(ws + off); off += CE * 384 * 2;
    float* h2 = (float*)(ws + off);                    off += CE * 128 * 4;

    k_split_pw<<<160, 256, 0, stream>>>(pw, pwb);
    k_cvt_w<<<(640 * 1920 + 255) / 256, 256, 0, stream>>>(wm0 + 512L * 1920, Wb0, 576, 640, 1920);
    k_cvt_w<<<(512 * 1536 + 255) / 256, 256, 0, stream>>>(wm1, Wb1, 512, 512, 1536);
    k_cvt_w<<<(384 * 1152 + 255) / 256, 256, 0, stream>>>(wm2, Wb2, 384, 384, 1152);
    k_cvt_w<<<(1920 * 128 + 255) / 256, 256, 0, stream>>>(w3, Wb3, 1920, 1920, 128);
    k_cvt_w_split<<<(128 * 384 + 255) / 256, 256, 0, stream>>>(w1, W1b, 128, 384);
    k_cvt_w_split<<<(128 * 128 + 255) / 256, 256, 0, stream>>>(w2, W2b, 128, 128);

    for (int e0 = 0; e0 < E; e0 += (int)CE) {
        int ec = (E - e0 < (int)CE) ? (E - e0) : (int)CE;
        int Mp  = (ec + 127) & ~127;
        int Mp2 = (2 * ec + 127) & ~127;
        int mt0 = Mp / 128, mt1 = Mp2 / 128;

        // --- radial MLP front as MFMA GEMMs ---
        k_build_xedge<<<dim3((ec * 384 + 255) / 256), 256, 0, stream>>>(
            ed, se, te, an, eidx, xeb, e0, ec, E);
        k_mfma_gemm<<<dim3(mt0, 1), 256, 0, stream>>>(
            xeb, W1b, b1, h1, 128, ec, 128, 1152);
        k_ln_silu<<<dim3((ec + 3) / 4), 256, 0, stream>>>(h1, g1, bb1, h1s, ec, 1);
        k_mfma_gemm<<<dim3(mt0, 1), 256, 0, stream>>>(
            h1s, W2b, b2, h2, 128, ec, 128, 384);
        k_ln_silu<<<dim3((ec + 3) / 4), 256, 0, stream>>>(h2, g2, bb2, h2b, ec, 0);

        k_mfma_gemm<<<dim3(mt0, 1920 / 128), 256, 0, stream>>>(
            h2b, Wb3, b3, wrad, 1920, ec, 1920, 128);

        k_build_mp<<<dim3(ec), 384, 0, stream>>>(
            x, ef, wgn, wrad, eidx, A0, A1, A2, e0, E);

        // y0 + y1 + y2 merged (independent GEMMs, one launch)
        k_mfma_gemm3<<<dim3(mt0 * 5 + mt1 * 7), 256, 0, stream>>>(
            A0, Wb0, bm0 + 512, y0, A1, Wb1, y1, A2, Wb2, y2, mt0, mt1, ec);

        k_combine_a<<<dim3(ec), 256, 0, stream>>>(wgn, y0, y1, y2, sfl, e0, (int)CE);

        int tilesTot = 0;
        for (int l = 0; l < 5; ++l) tilesTot += (ec * (2 * l + 1) + 127) >> 7;
        k_proj_gemm<<<dim3(tilesTot), 256, 0, stream>>>(
            sfl, pwb, pb, out + (long)e0 * 3200, ec, (int)CE);
    }
}